// Round 6
// baseline (1776.440 us; speedup 1.0000x reference)
//
#include <hip/hip_runtime.h>
#include <hip/hip_cooperative_groups.h>

namespace cg = cooperative_groups;

#define N_NODES 6000
#define DEG_    16
#define N_EDGES (N_NODES*DEG_)

typedef __bf16 bf16x8 __attribute__((ext_vector_type(8)));
typedef float floatx4 __attribute__((ext_vector_type(4)));

__device__ __forceinline__ float silu_f(float v) {
    return v * __builtin_amdgcn_rcpf(1.0f + __expf(-v));
}
__device__ __forceinline__ float b2f(unsigned short u) {
    union { unsigned int i; float f; } v; v.i = ((unsigned int)u) << 16; return v.f;
}
__device__ __forceinline__ unsigned short f2b(float f) {
    union { float f; unsigned int i; } v; v.f = f;
    unsigned int r = (v.i + 0x7FFFu + ((v.i >> 16) & 1u)) >> 16;
    return (unsigned short)r;
}

#define WSRC_OFF 0
#define WDST_OFF 49152
#define WEDGE_OFF 98304
#define W1_OFF 147456
#define W2_OFF 344064
#define WTOTAL 1130496

#define APITCH 40   // bf16 pitch: 80B rows, stride 20 dwords -> 2-way banks (free)
#define FP     72   // ffn staging pitch: 144B rows, stride 36 dwords -> 2-way banks

struct GSm { unsigned short As[128*APITCH]; unsigned short Bs[64*APITCH]; };                 // 15360 B
struct ASm { float xij[16][68]; float rh[16][4]; float logit[16][17]; float aw[16][17]; float w[16]; };
struct FSm { unsigned short Xs[64*FP]; unsigned short W1s[64*FP]; unsigned short Hs[64*FP]; }; // 27648 B
union  SmemU { GSm g; ASm a; FSm f; float red[256]; };

struct MegaParams {
    const float* r; const int* an; const int* src;
    const float* emb; const float* Wsrc; const float* bsrc;
    const float* Wdst; const float* bdst; const float* Wedge; const float* bedge;
    const float* attn; const float* W1; const float* b1;
    const float* W2; const float* b2; const float* Wfc; const float* bfc;
    float* dd; float* rhat;
    unsigned short* wbf; unsigned short* x; unsigned short* xjxi;
    unsigned short* eproj; unsigned short* xn;
    float* out;
};

// ---------- GEMM tile: C[m0.., bc] = act(A @ B^T + bias), TM x 64 ----------
template<int ACT, int RBF, int TM>
__device__ __forceinline__ void gemm_tile(GSm& g,
    const unsigned short* __restrict__ A, int lda,
    const unsigned short* __restrict__ Brow, int ldb,
    const float* __restrict__ bias,          // indexed by bc (0..63)
    unsigned short* __restrict__ C, int ldc, // pre-offset to column block
    int m0, int M, int K, const float* __restrict__ dvec) {
    constexpr int WR = TM/4;
    constexpr int FC = WR/16;
    const int t = threadIdx.x;
    const int w = t >> 6, lane = t & 63, lr = lane & 15, lq = lane >> 4;
    floatx4 acc[FC][4] = {};
    for (int k0 = 0; k0 < K; k0 += 32) {
        #pragma unroll
        for (int it = 0; it < TM/64; ++it) {
            int i = t + it*256;
            int row = i >> 2, chk = i & 3;
            int gm = m0 + row;
            uint4 val = make_uint4(0,0,0,0);
            if (RBF) {
                const float gamma = 31.875f;
                const float step  = 8.0f / 255.0f;
                float dv = dvec[gm];               // RBF path: M % TM == 0
                int kb = k0 + chk*8;
                unsigned short h[8];
                #pragma unroll
                for (int j = 0; j < 8; ++j) {
                    float tt = dv - (float)(kb+j) * step;
                    h[j] = f2b(__expf(-gamma * tt * tt));
                }
                val = *(uint4*)h;
            } else if (gm < M) {
                val = *(const uint4*)(A + (size_t)gm*lda + k0 + chk*8);
            }
            *(uint4*)(&g.As[row*APITCH + chk*8]) = val;
        }
        {
            int row = t >> 2, chk = t & 3;
            *(uint4*)(&g.Bs[row*APITCH + chk*8]) =
                *(const uint4*)(Brow + (size_t)row*ldb + k0 + chk*8);
        }
        __syncthreads();
        bf16x8 af[FC], bfr[4];
        #pragma unroll
        for (int fc = 0; fc < FC; ++fc)
            af[fc] = *(const bf16x8*)(&g.As[(w*WR + fc*16 + lr)*APITCH + lq*8]);
        #pragma unroll
        for (int ns = 0; ns < 4; ++ns)
            bfr[ns] = *(const bf16x8*)(&g.Bs[(ns*16 + lr)*APITCH + lq*8]);
        #pragma unroll
        for (int ns = 0; ns < 4; ++ns)
            #pragma unroll
            for (int fc = 0; fc < FC; ++fc)
                acc[fc][ns] = __builtin_amdgcn_mfma_f32_16x16x32_bf16(af[fc], bfr[ns], acc[fc][ns], 0,0,0);
        __syncthreads();
    }
    #pragma unroll
    for (int ns = 0; ns < 4; ++ns) {
        int bc = ns*16 + lr;
        float bv = bias[bc];
        #pragma unroll
        for (int fc = 0; fc < FC; ++fc) {
            #pragma unroll
            for (int rg = 0; rg < 4; ++rg) {
                int gm = m0 + w*WR + fc*16 + lq*4 + rg;
                if (gm < M) {
                    float v = acc[fc][ns][rg] + bv;
                    if (ACT) v = silu_f(v);
                    C[(size_t)gm*ldc + bc] = f2b(v);
                }
            }
        }
    }
}

// ---------- angle attention for one node ----------
__device__ __forceinline__ void angle_node(ASm& s, int node,
    const unsigned short* __restrict__ xjxi,
    const unsigned short* __restrict__ eproj,   // pre-offset by l*64, row stride 192
    const float* __restrict__ rhat,
    const int* __restrict__ src,
    const float* __restrict__ attn,             // pre-offset by l*64 (wave-uniform)
    unsigned short* __restrict__ xn) {
    const int t = threadIdx.x;
    if (t < 16) {
        float4 rv = *(const float4*)(rhat + (size_t)(node*DEG_ + t)*4);
        s.rh[t][0] = rv.x; s.rh[t][1] = rv.y; s.rh[t][2] = rv.z; s.rh[t][3] = 0.f;
    }
    if (t < 128) {
        int p = t >> 3, c8 = t & 7;
        int e = node*DEG_ + p;
        int se = src[e];
        uint4 aj = *(const uint4*)(xjxi + (size_t)se*128 + c8*8);
        uint4 ai = *(const uint4*)(xjxi + (size_t)node*128 + 64 + c8*8);
        uint4 ae = *(const uint4*)(eproj + (size_t)e*192 + c8*8);
        const unsigned short* pj = (const unsigned short*)&aj;
        const unsigned short* pi = (const unsigned short*)&ai;
        const unsigned short* pe = (const unsigned short*)&ae;
        #pragma unroll
        for (int j = 0; j < 8; ++j)
            s.xij[p][c8*8 + j] = b2f(pj[j]) + b2f(pi[j]) + b2f(pe[j]);
    }
    __syncthreads();
    if (t < 240) {
        int p  = t / 15;
        int qq = t - p*15;
        int q  = qq + (qq >= p ? 1 : 0);
        float c = s.rh[p][0]*s.rh[q][0] + s.rh[p][1]*s.rh[q][1] + s.rh[p][2]*s.rh[q][2];
        c = fminf(fmaxf(c, -0.999999f), 0.999999f);
        float c2 = 2.0f * c;
        float tk0 = 1.0f, tk1 = c, acc = 0.f;
        const float* xp = &s.xij[p][0];
        const float* xq = &s.xij[q][0];
        #pragma unroll
        for (int k0 = 0; k0 < 64; k0 += 4) {
            float4 xp4 = *(const float4*)(xp + k0);
            float4 xq4 = *(const float4*)(xq + k0);
            float a0 = attn[k0+0], a1 = attn[k0+1], a2 = attn[k0+2], a3 = attn[k0+3];
            float v0 = tk0 + xp4.x + xq4.x;
            acc = fmaf(a0, silu_f(v0), acc);
            { float tn2 = c2*tk1 - tk0; tk0 = tk1; tk1 = tn2; }
            float v1 = tk0 + xp4.y + xq4.y;
            acc = fmaf(a1, silu_f(v1), acc);
            { float tn2 = c2*tk1 - tk0; tk0 = tk1; tk1 = tn2; }
            float v2 = tk0 + xp4.z + xq4.z;
            acc = fmaf(a2, silu_f(v2), acc);
            { float tn2 = c2*tk1 - tk0; tk0 = tk1; tk1 = tn2; }
            float v3 = tk0 + xp4.w + xq4.w;
            acc = fmaf(a3, silu_f(v3), acc);
            { float tn2 = c2*tk1 - tk0; tk0 = tk1; tk1 = tn2; }
        }
        s.logit[p][q] = acc;
    }
    __syncthreads();
    if (t < 16) {
        int q = t;
        float mx = -1e30f;
        #pragma unroll
        for (int p = 0; p < 16; ++p) if (p != q) mx = fmaxf(mx, s.logit[p][q]);
        float ssum = 0.f;
        float ex[16];
        #pragma unroll
        for (int p = 0; p < 16; ++p) {
            float e = (p == q) ? 0.f : __expf(s.logit[p][q] - mx);
            ex[p] = e; ssum += e;
        }
        float inv = 1.0f / ssum;
        #pragma unroll
        for (int p = 0; p < 16; ++p) s.aw[p][q] = ex[p] * inv;
    }
    __syncthreads();
    if (t < 16) {
        int p = t;
        float sw = 0.f;
        #pragma unroll
        for (int q = 0; q < 16; ++q) sw += s.aw[p][q];
        s.w[p] = sw;
    }
    __syncthreads();
    if (t < 64) {
        float acc = 0.f;
        #pragma unroll
        for (int p = 0; p < 16; ++p) acc += s.w[p] * s.xij[p][t];
        xn[(size_t)node*64 + t] = f2b(acc);
    }
    __syncthreads();   // protect smem reuse on next node iteration
}

// ---------- fused FFN tile: 64 nodes (m0) x 64 out-cols (n0) ----------
// h chunk kept in LDS (bf16); W2 B-fragments read directly from global (L2).
__device__ __forceinline__ void ffn_tile(FSm& f, int m0, int n0,
    const unsigned short* __restrict__ xn,   // [6000,64]
    const unsigned short* __restrict__ W1l,  // [1024,64]
    const float* __restrict__ b1l,           // [1024]
    const unsigned short* __restrict__ W2l,  // [256,1024]
    const float* __restrict__ b2l,           // [256]
    unsigned short* __restrict__ xout,       // [6000,256]
    int M) {
    const int t = threadIdx.x;
    const int w = t >> 6, lane = t & 63, lr = lane & 15, lq = lane >> 4;
    #pragma unroll
    for (int it = 0; it < 2; ++it) {        // stage Xs [64 x 64]
        int i = t + it*256;
        int row = i >> 3, chk = i & 7;
        int gm = m0 + row;
        uint4 v = make_uint4(0,0,0,0);
        if (gm < M) v = *(const uint4*)(xn + (size_t)gm*64 + chk*8);
        *(uint4*)(&f.Xs[row*FP + chk*8]) = v;
    }
    floatx4 acc2[4] = {};
    for (int c = 0; c < 16; ++c) {
        #pragma unroll
        for (int it = 0; it < 2; ++it) {    // stage W1 chunk [64 ff x 64 msg]
            int i = t + it*256;
            int row = i >> 3, chk = i & 7;
            *(uint4*)(&f.W1s[row*FP + chk*8]) =
                *(const uint4*)(W1l + (size_t)(c*64+row)*64 + chk*8);
        }
        __syncthreads();
        floatx4 acc1[4] = {};
        #pragma unroll
        for (int k0 = 0; k0 < 64; k0 += 32) {
            bf16x8 a = *(const bf16x8*)(&f.Xs[(w*16+lr)*FP + k0 + lq*8]);
            #pragma unroll
            for (int ns = 0; ns < 4; ++ns) {
                bf16x8 b = *(const bf16x8*)(&f.W1s[(ns*16+lr)*FP + k0 + lq*8]);
                acc1[ns] = __builtin_amdgcn_mfma_f32_16x16x32_bf16(a, b, acc1[ns], 0,0,0);
            }
        }
        #pragma unroll
        for (int ns = 0; ns < 4; ++ns) {    // silu -> Hs (C-layout scatter, bf16)
            float bv = b1l[c*64 + ns*16 + lr];
            #pragma unroll
            for (int rg = 0; rg < 4; ++rg) {
                int hr = w*16 + lq*4 + rg;
                f.Hs[hr*FP + ns*16 + lr] = f2b(silu_f(acc1[ns][rg] + bv));
            }
        }
        __syncthreads();
        #pragma unroll
        for (int k0 = 0; k0 < 64; k0 += 32) {   // GEMM2: acc2 += h @ W2c^T
            bf16x8 a = *(const bf16x8*)(&f.Hs[(w*16+lr)*FP + k0 + lq*8]);
            #pragma unroll
            for (int ns = 0; ns < 4; ++ns) {
                bf16x8 b = *(const bf16x8*)(W2l + (size_t)(n0 + ns*16 + lr)*1024 + c*64 + k0 + lq*8);
                acc2[ns] = __builtin_amdgcn_mfma_f32_16x16x32_bf16(a, b, acc2[ns], 0,0,0);
            }
        }
        __syncthreads();
    }
    #pragma unroll
    for (int ns = 0; ns < 4; ++ns) {
        int bc = ns*16 + lr;
        float bv = b2l[n0 + bc];
        #pragma unroll
        for (int rg = 0; rg < 4; ++rg) {
            int gm = m0 + w*16 + lq*4 + rg;
            if (gm < M) xout[(size_t)gm*256 + n0 + bc] = f2b(acc2[ns][rg] + bv);
        }
    }
}

// ---------- the mega kernel ----------
__global__ __launch_bounds__(256, 4) void mega(MegaParams P) {
    cg::grid_group grid = cg::this_grid();
    __shared__ SmemU sm;
    const int t = threadIdx.x;
    const int bid = blockIdx.x;
    const int NB = gridDim.x;

    // ---- P0: weight cvt + embed + geom + out init ----
    for (int i = bid*256 + t; i < WTOTAL; i += NB*256) {
        float v;
        if      (i < WDST_OFF)  v = P.Wsrc[i];
        else if (i < WEDGE_OFF) v = P.Wdst[i - WDST_OFF];
        else if (i < W1_OFF)    v = P.Wedge[i - WEDGE_OFF];
        else if (i < W2_OFF)    v = P.W1[i - W1_OFF];
        else                    v = P.W2[i - W2_OFF];
        P.wbf[i] = f2b(v);
    }
    for (int i = bid*256 + t; i < N_NODES*256; i += NB*256) {
        int node = i >> 8, c = i & 255;
        P.x[(size_t)node*256 + c] = f2b(P.emb[(size_t)P.an[node]*256 + c]);
    }
    for (int e = bid*256 + t; e < N_EDGES; e += NB*256) {
        float xx = P.r[e*3+0], yy = P.r[e*3+1], zz = P.r[e*3+2];
        float n = sqrtf(xx*xx + yy*yy + zz*zz);
        P.dd[e] = n;
        float inv = 1.0f / n;
        *(float4*)(P.rhat + (size_t)e*4) = make_float4(xx*inv, yy*inv, zz*inv, 0.f);
    }
    if (bid == 0 && t == 0) P.out[0] = P.bfc[0];
    __threadfence();
    grid.sync();

    // ---- P1: eproj = RBF(d) @ Wedge^T + bedge, [E,192] ----
    for (int tile = bid; tile < 3*750; tile += NB) {
        int nb = tile % 3, mb = tile / 3;
        gemm_tile<0,1,128>(sm.g, (const unsigned short*)nullptr, 0,
            P.wbf + WEDGE_OFF + nb*64*256, 256,
            P.bedge + nb*64,
            P.eproj + nb*64, 192,
            mb*128, N_EDGES, 256, P.dd);
    }
    __threadfence();
    grid.sync();

    for (int l = 0; l < 3; ++l) {
        // ---- P2: dual projection xj|xi ----
        for (int tile = bid; tile < 2*94; tile += NB) {
            int which = tile & 1, mb = tile >> 1;
            const unsigned short* B = P.wbf + (which ? WDST_OFF : WSRC_OFF) + l*16384;
            const float* bias = (which ? P.bdst : P.bsrc) + l*64;
            gemm_tile<0,0,64>(sm.g, P.x, 256, B, 256, bias,
                P.xjxi + which*64, 128, mb*64, N_NODES, 256,
                (const float*)nullptr);
        }
        __threadfence();
        grid.sync();
        // ---- P3: angle attention -> xn ----
        for (int node = bid; node < N_NODES; node += NB)
            angle_node(sm.a, node, P.xjxi, P.eproj + l*64, P.rhat, P.src,
                       P.attn + l*64, P.xn);
        __threadfence();
        grid.sync();
        // ---- P4: fused FFN -> x ----
        for (int tile = bid; tile < 94*4; tile += NB) {
            int mb = tile >> 2, nb = tile & 3;
            ffn_tile(sm.f, mb*64, nb*64, P.xn,
                P.wbf + W1_OFF + l*65536, P.b1 + l*1024,
                P.wbf + W2_OFF + l*262144, P.b2 + l*256,
                P.x, N_NODES);
        }
        __threadfence();
        grid.sync();
    }

    // ---- P5: reduce out = bfc + mean(x @ Wfc) ----
    {
        float local = 0.f;
        for (int i = bid; i < N_NODES; i += NB)
            local += b2f(P.x[(size_t)i*256 + t]);
        local *= P.Wfc[t];
        sm.red[t] = local;
        __syncthreads();
        for (int off = 128; off > 0; off >>= 1) {
            if (t < off) sm.red[t] += sm.red[t+off];
            __syncthreads();
        }
        if (t == 0) atomicAdd(P.out, sm.red[0] * (1.0f/(float)N_NODES));
    }
}

extern "C" void kernel_launch(void* const* d_in, const int* in_sizes, int n_in,
                              void* d_out, int out_size, void* d_ws, size_t ws_size,
                              hipStream_t stream) {
    (void)in_sizes; (void)n_in; (void)out_size; (void)ws_size;
    char* ws = (char*)d_ws;
    MegaParams P;
    P.r    = (const float*)d_in[0];
    P.an   = (const int*)  d_in[1];
    P.src  = (const int*)  d_in[2];
    P.emb  = (const float*)d_in[6];
    P.Wsrc = (const float*)d_in[7];
    P.bsrc = (const float*)d_in[8];
    P.Wdst = (const float*)d_in[9];
    P.bdst = (const float*)d_in[10];
    P.Wedge= (const float*)d_in[11];
    P.bedge= (const float*)d_in[12];
    P.attn = (const float*)d_in[13];
    P.W1   = (const float*)d_in[14];
    P.b1   = (const float*)d_in[15];
    P.W2   = (const float*)d_in[16];
    P.b2   = (const float*)d_in[17];
    P.Wfc  = (const float*)d_in[18];
    P.bfc  = (const float*)d_in[19];
    P.dd    = (float*)(ws);
    P.rhat  = (float*)(ws + 384000);
    P.wbf   = (unsigned short*)(ws + 1920000);
    P.x     = (unsigned short*)(ws + 4180992);
    P.xjxi  = (unsigned short*)(ws + 7252992);
    P.eproj = (unsigned short*)(ws + 8788992);
    P.xn    = (unsigned short*)(ws + 45652992);
    P.out   = (float*)d_out;

    // Size the cooperative grid from the occupancy API (never hardcode):
    int dev = 0;
    hipGetDevice(&dev);
    int num_cu = 256;
    hipDeviceGetAttribute(&num_cu, hipDeviceAttributeMultiprocessorCount, dev);
    int blk_per_cu = 1;
    hipOccupancyMaxActiveBlocksPerMultiprocessor(&blk_per_cu, (const void*)mega, 256, 0);
    if (blk_per_cu < 1) blk_per_cu = 1;
    int nblk = blk_per_cu * num_cu;
    if (nblk > 1024) nblk = 1024;

    void* kargs[] = { (void*)&P };
    hipLaunchCooperativeKernel((void*)mega, dim3(nblk), dim3(256), kargs, 0, stream);
}

// Round 7
// 488.164 us; speedup vs baseline: 3.6390x; 3.6390x over previous
//
#include <hip/hip_runtime.h>

#define N_NODES 6000
#define DEG_    16
#define N_EDGES (N_NODES*DEG_)
#define D_MODEL 256
#define D_MSG   64
#define D_FF    1024

typedef __bf16 bf16x8 __attribute__((ext_vector_type(8)));
typedef float floatx4 __attribute__((ext_vector_type(4)));

__device__ __forceinline__ float silu_f(float v) {
    return v * __builtin_amdgcn_rcpf(1.0f + __expf(-v));
}
__device__ __forceinline__ float b2f(unsigned short u) {
    union { unsigned int i; float f; } v; v.i = ((unsigned int)u) << 16; return v.f;
}
__device__ __forceinline__ unsigned short f2b(float f) {
    union { float f; unsigned int i; } v; v.f = f;
    unsigned int r = (v.i + 0x7FFFu + ((v.i >> 16) & 1u)) >> 16;
    return (unsigned short)r;
}

// ---------------- fused prep: weight cvt + embed + geometry + out init ----------------
#define WSRC_OFF 0
#define WDST_OFF 49152
#define WEDGE_OFF 98304
#define W1_OFF 147456
#define W2_OFF 344064
#define WTOTAL 1130496
#define CVT_BLOCKS ((WTOTAL+255)/256)          // 4416
#define GEOM_BLOCKS (N_EDGES/256)              // 375
__global__ __launch_bounds__(256) void prep_kernel(
    const float* __restrict__ Wsrc, const float* __restrict__ Wdst,
    const float* __restrict__ Wedge, const float* __restrict__ W1,
    const float* __restrict__ W2, unsigned short* __restrict__ wdst_out,
    const int* __restrict__ an, const float* __restrict__ emb,
    unsigned short* __restrict__ x,
    const float* __restrict__ r, float* __restrict__ d, float* __restrict__ rhat,
    float* __restrict__ out, const float* __restrict__ bfc) {
    int b = blockIdx.x;
    int t = threadIdx.x;
    if (b == 0 && t == 0) out[0] = bfc[0];
    if (b < CVT_BLOCKS) {
        int i = b*256 + t;
        if (i < WTOTAL) {
            float v;
            if      (i < WDST_OFF)  v = Wsrc[i];
            else if (i < WEDGE_OFF) v = Wdst[i - WDST_OFF];
            else if (i < W1_OFF)    v = Wedge[i - WEDGE_OFF];
            else if (i < W2_OFF)    v = W1[i - W1_OFF];
            else                    v = W2[i - W2_OFF];
            wdst_out[i] = f2b(v);
        }
    } else if (b < CVT_BLOCKS + N_NODES) {
        int i = b - CVT_BLOCKS;
        x[i*D_MODEL + t] = f2b(emb[an[i]*D_MODEL + t]);
    } else {
        int e = (b - CVT_BLOCKS - N_NODES)*256 + t;
        float xx = r[e*3+0], yy = r[e*3+1], zz = r[e*3+2];
        float n = sqrtf(xx*xx + yy*yy + zz*zz);
        d[e] = n;
        float inv = 1.0f / n;
        *(float4*)(rhat + (size_t)e*4) = make_float4(xx*inv, yy*inv, zz*inv, 0.f);
    }
}

// ---------------- MFMA bf16 GEMM: C = bf16(act(A @ B^T + bias)) ----------------
#define APITCH 40
template<int ACT, int RBF, int DUALB, int TM>
__global__ __launch_bounds__(256) void mgemm(
    const unsigned short* __restrict__ A, int lda,
    const unsigned short* __restrict__ B1, const unsigned short* __restrict__ B2, int ldb,
    const float* __restrict__ bias1, const float* __restrict__ bias2,
    unsigned short* __restrict__ C, int ldc, int M, int K,
    const float* __restrict__ dvec) {
    constexpr int WR = TM/4;       // rows per wave
    constexpr int FC = WR/16;      // 16-row fragments per wave
    __shared__ __align__(16) unsigned short As[TM*APITCH];
    __shared__ __align__(16) unsigned short Bs[64*APITCH];
    const int t = threadIdx.x;
    const int w = t >> 6;
    const int lane = t & 63;
    const int lr = lane & 15;
    const int lq = lane >> 4;
    const int n0 = blockIdx.x * 64;
    const int m0 = blockIdx.y * TM;
    const unsigned short* B = B1;
    const float* bias = bias1;
    if (DUALB && blockIdx.x == 1) { B = B2; bias = bias2; }
    const unsigned short* Brow = DUALB ? B : (B + (size_t)n0*ldb);

    floatx4 acc[FC][4] = {};

    for (int k0 = 0; k0 < K; k0 += 32) {
        #pragma unroll
        for (int it = 0; it < TM/64; ++it) {
            int i = t + it*256;
            int row = i >> 2, chk = i & 3;
            int gm = m0 + row;
            uint4 val = make_uint4(0,0,0,0);
            if (RBF) {
                const float gamma = 31.875f;
                const float step  = 8.0f / 255.0f;
                float dv = dvec[gm];          // RBF path: M % TM == 0
                int kb = k0 + chk*8;
                unsigned short h[8];
                #pragma unroll
                for (int j = 0; j < 8; ++j) {
                    float tt = dv - (float)(kb+j) * step;
                    h[j] = f2b(__expf(-gamma * tt * tt));
                }
                val = *(uint4*)h;
            } else if (gm < M) {
                val = *(const uint4*)(A + (size_t)gm*lda + k0 + chk*8);
            }
            *(uint4*)(&As[row*APITCH + chk*8]) = val;
        }
        {
            int row = t >> 2, chk = t & 3;
            *(uint4*)(&Bs[row*APITCH + chk*8]) =
                *(const uint4*)(Brow + (size_t)row*ldb + k0 + chk*8);
        }
        __syncthreads();
        bf16x8 af[FC], bfr[4];
        #pragma unroll
        for (int fc = 0; fc < FC; ++fc)
            af[fc] = *(const bf16x8*)(&As[(w*WR + fc*16 + lr)*APITCH + lq*8]);
        #pragma unroll
        for (int ns = 0; ns < 4; ++ns)
            bfr[ns] = *(const bf16x8*)(&Bs[(ns*16 + lr)*APITCH + lq*8]);
        #pragma unroll
        for (int ns = 0; ns < 4; ++ns)
            #pragma unroll
            for (int fc = 0; fc < FC; ++fc)
                acc[fc][ns] = __builtin_amdgcn_mfma_f32_16x16x32_bf16(af[fc], bfr[ns], acc[fc][ns], 0,0,0);
        __syncthreads();
    }
    #pragma unroll
    for (int ns = 0; ns < 4; ++ns) {
        int bc = ns*16 + lr;
        float bv = bias[DUALB ? bc : (n0 + bc)];
        #pragma unroll
        for (int fc = 0; fc < FC; ++fc) {
            #pragma unroll
            for (int rg = 0; rg < 4; ++rg) {
                int gm = m0 + w*WR + fc*16 + lq*4 + rg;
                if (gm < M) {
                    float v = acc[fc][ns][rg] + bv;
                    if (ACT) v = silu_f(v);
                    C[(size_t)gm*ldc + n0 + bc] = f2b(v);
                }
            }
        }
    }
}

// ---------------- fused FFN: x[64 nodes, 64 cols] = ffn2(silu(ffn1(xn))) ----------------
// grid (4, 94): nb = out col-block, mb = node row-block. h chunk in LDS bf16;
// W2 B-fragments read directly from global (L2-resident, 1 MB/layer).
#define FP 72
__global__ __launch_bounds__(256) void ffn_kernel(
    const unsigned short* __restrict__ xn,   // [6000,64]
    const unsigned short* __restrict__ W1l,  // [1024,64] bf16
    const float* __restrict__ b1l,           // [1024]
    const unsigned short* __restrict__ W2l,  // [256,1024] bf16
    const float* __restrict__ b2l,           // [256]
    unsigned short* __restrict__ xout,       // [6000,256]
    int M) {
    __shared__ __align__(16) unsigned short Xs[64*FP];
    __shared__ __align__(16) unsigned short W1s[64*FP];
    __shared__ __align__(16) unsigned short Hs[64*FP];
    const int t = threadIdx.x;
    const int w = t >> 6, lane = t & 63, lr = lane & 15, lq = lane >> 4;
    const int n0 = blockIdx.x * 64;
    const int m0 = blockIdx.y * 64;
    #pragma unroll
    for (int it = 0; it < 2; ++it) {        // stage Xs [64 x 64]
        int i = t + it*256;
        int row = i >> 3, chk = i & 7;
        int gm = m0 + row;
        uint4 v = make_uint4(0,0,0,0);
        if (gm < M) v = *(const uint4*)(xn + (size_t)gm*64 + chk*8);
        *(uint4*)(&Xs[row*FP + chk*8]) = v;
    }
    floatx4 acc2[4] = {};
    for (int c = 0; c < 16; ++c) {
        #pragma unroll
        for (int it = 0; it < 2; ++it) {    // stage W1 chunk [64 ff x 64 msg]
            int i = t + it*256;
            int row = i >> 3, chk = i & 7;
            *(uint4*)(&W1s[row*FP + chk*8]) =
                *(const uint4*)(W1l + (size_t)(c*64+row)*64 + chk*8);
        }
        __syncthreads();
        floatx4 acc1[4] = {};
        #pragma unroll
        for (int k0 = 0; k0 < 64; k0 += 32) {
            bf16x8 a = *(const bf16x8*)(&Xs[(w*16+lr)*FP + k0 + lq*8]);
            #pragma unroll
            for (int ns = 0; ns < 4; ++ns) {
                bf16x8 b = *(const bf16x8*)(&W1s[(ns*16+lr)*FP + k0 + lq*8]);
                acc1[ns] = __builtin_amdgcn_mfma_f32_16x16x32_bf16(a, b, acc1[ns], 0,0,0);
            }
        }
        #pragma unroll
        for (int ns = 0; ns < 4; ++ns) {    // silu -> Hs (C-layout scatter, bf16)
            float bv = b1l[c*64 + ns*16 + lr];
            #pragma unroll
            for (int rg = 0; rg < 4; ++rg) {
                int hr = w*16 + lq*4 + rg;
                Hs[hr*FP + ns*16 + lr] = f2b(silu_f(acc1[ns][rg] + bv));
            }
        }
        __syncthreads();
        #pragma unroll
        for (int k0 = 0; k0 < 64; k0 += 32) {   // GEMM2: acc2 += h @ W2c^T
            bf16x8 a = *(const bf16x8*)(&Hs[(w*16+lr)*FP + k0 + lq*8]);
            #pragma unroll
            for (int ns = 0; ns < 4; ++ns) {
                bf16x8 b = *(const bf16x8*)(W2l + (size_t)(n0 + ns*16 + lr)*1024 + c*64 + k0 + lq*8);
                acc2[ns] = __builtin_amdgcn_mfma_f32_16x16x32_bf16(a, b, acc2[ns], 0,0,0);
            }
        }
        __syncthreads();
    }
    #pragma unroll
    for (int ns = 0; ns < 4; ++ns) {
        int bc = ns*16 + lr;
        float bv = b2l[n0 + bc];
        #pragma unroll
        for (int rg = 0; rg < 4; ++rg) {
            int gm = m0 + w*16 + lq*4 + rg;
            if (gm < M) xout[(size_t)gm*256 + n0 + bc] = f2b(acc2[ns][rg] + bv);
        }
    }
}

// ---------------- angle attention, one block per node (bf16 IO, fp32 math) ----------------
#define XSTRIDE 68
__global__ __launch_bounds__(256) void angle_kernel(
    const unsigned short* __restrict__ xjxi,   // [N,128] bf16: 0..63 xj, 64..127 xi
    const unsigned short* __restrict__ eproj,  // [E,192] bf16, pre-offset by l*64
    const float* __restrict__ rhat,            // [E,4]
    const int*   __restrict__ src,             // [E]
    const float* __restrict__ attn,            // [64] pre-offset, wave-uniform
    unsigned short* __restrict__ xn) {         // [N,64] bf16
    __shared__ __align__(16) float s_xij[16][XSTRIDE];
    __shared__ float s_rhat[16][4];
    __shared__ float s_logit[16][17];
    __shared__ float s_a[16][17];
    __shared__ float s_w[16];
    int node = blockIdx.x;
    int t = threadIdx.x;

    if (t < 16) {
        float4 rv = *(const float4*)(rhat + (size_t)(node*DEG_ + t)*4);
        s_rhat[t][0] = rv.x; s_rhat[t][1] = rv.y; s_rhat[t][2] = rv.z; s_rhat[t][3] = 0.f;
    }
    if (t < 128) {
        int p = t >> 3, c8 = t & 7;
        int e = node*DEG_ + p;
        int se = src[e];
        uint4 aj = *(const uint4*)(xjxi + (size_t)se*128 + c8*8);
        uint4 ai = *(const uint4*)(xjxi + (size_t)node*128 + 64 + c8*8);
        uint4 ae = *(const uint4*)(eproj + (size_t)e*192 + c8*8);
        const unsigned short* pj = (const unsigned short*)&aj;
        const unsigned short* pi = (const unsigned short*)&ai;
        const unsigned short* pe = (const unsigned short*)&ae;
        #pragma unroll
        for (int j = 0; j < 8; ++j)
            s_xij[p][c8*8 + j] = b2f(pj[j]) + b2f(pi[j]) + b2f(pe[j]);
    }
    __syncthreads();
    if (t < 240) {
        int p  = t / 15;
        int qq = t - p*15;
        int q  = qq + (qq >= p ? 1 : 0);
        float c = s_rhat[p][0]*s_rhat[q][0] + s_rhat[p][1]*s_rhat[q][1] + s_rhat[p][2]*s_rhat[q][2];
        c = fminf(fmaxf(c, -0.999999f), 0.999999f);
        float c2  = 2.0f * c;
        float tk0 = 1.0f;
        float tk1 = c;
        float acc = 0.f;
        const float* xp = &s_xij[p][0];
        const float* xq = &s_xij[q][0];
        #pragma unroll
        for (int k0 = 0; k0 < 64; k0 += 4) {
            float4 xp4 = *(const float4*)(xp + k0);
            float4 xq4 = *(const float4*)(xq + k0);
            float a0 = attn[k0+0], a1 = attn[k0+1], a2 = attn[k0+2], a3 = attn[k0+3];
            float v0 = tk0 + xp4.x + xq4.x;
            acc = fmaf(a0, silu_f(v0), acc);
            { float tn2 = c2*tk1 - tk0; tk0 = tk1; tk1 = tn2; }
            float v1 = tk0 + xp4.y + xq4.y;
            acc = fmaf(a1, silu_f(v1), acc);
            { float tn2 = c2*tk1 - tk0; tk0 = tk1; tk1 = tn2; }
            float v2 = tk0 + xp4.z + xq4.z;
            acc = fmaf(a2, silu_f(v2), acc);
            { float tn2 = c2*tk1 - tk0; tk0 = tk1; tk1 = tn2; }
            float v3 = tk0 + xp4.w + xq4.w;
            acc = fmaf(a3, silu_f(v3), acc);
            { float tn2 = c2*tk1 - tk0; tk0 = tk1; tk1 = tn2; }
        }
        s_logit[p][q] = acc;
    }
    __syncthreads();
    if (t < 16) {
        int q = t;
        float mx = -1e30f;
        #pragma unroll
        for (int p = 0; p < 16; ++p) if (p != q) mx = fmaxf(mx, s_logit[p][q]);
        float ssum = 0.f;
        float ex[16];
        #pragma unroll
        for (int p = 0; p < 16; ++p) {
            float e = (p == q) ? 0.f : __expf(s_logit[p][q] - mx);
            ex[p] = e; ssum += e;
        }
        float inv = 1.0f / ssum;
        #pragma unroll
        for (int p = 0; p < 16; ++p) s_a[p][q] = ex[p] * inv;
    }
    __syncthreads();
    if (t < 16) {
        int p = t;
        float sw = 0.f;
        #pragma unroll
        for (int q = 0; q < 16; ++q) sw += s_a[p][q];
        s_w[p] = sw;
    }
    __syncthreads();
    if (t < 64) {
        float acc = 0.f;
        #pragma unroll
        for (int p = 0; p < 16; ++p) acc += s_w[p] * s_xij[p][t];
        xn[(size_t)node*64 + t] = f2b(acc);
    }
}

// ---------------- final: out += mean_i (x[i] . Wfc)  (out pre-set to bfc by prep) ----------------
__global__ __launch_bounds__(256) void reduce_kernel(const unsigned short* __restrict__ x,
    const float* __restrict__ Wfc, float* __restrict__ out) {
    __shared__ float s[256];
    int t = threadIdx.x;
    float local = 0.f;
    for (int i = blockIdx.x; i < N_NODES; i += gridDim.x) local += b2f(x[(size_t)i*D_MODEL + t]);
    local *= Wfc[t];
    s[t] = local; __syncthreads();
    for (int off = 128; off > 0; off >>= 1) {
        if (t < off) s[t] += s[t+off];
        __syncthreads();
    }
    if (t == 0) atomicAdd(out, s[0] * (1.0f/(float)N_NODES));
}

extern "C" void kernel_launch(void* const* d_in, const int* in_sizes, int n_in,
                              void* d_out, int out_size, void* d_ws, size_t ws_size,
                              hipStream_t stream) {
    (void)in_sizes; (void)n_in; (void)out_size; (void)ws_size;
    const float* r    = (const float*)d_in[0];
    const int*   an   = (const int*)  d_in[1];
    const int*   src  = (const int*)  d_in[2];
    const float* emb  = (const float*)d_in[6];
    const float* Wsrc = (const float*)d_in[7];
    const float* bsrc = (const float*)d_in[8];
    const float* Wdst = (const float*)d_in[9];
    const float* bdst = (const float*)d_in[10];
    const float* Wedge= (const float*)d_in[11];
    const float* bedge= (const float*)d_in[12];
    const float* attn = (const float*)d_in[13];
    const float* W1   = (const float*)d_in[14];
    const float* b1   = (const float*)d_in[15];
    const float* W2   = (const float*)d_in[16];
    const float* b2   = (const float*)d_in[17];
    const float* Wfc  = (const float*)d_in[18];
    const float* bfc  = (const float*)d_in[19];

    char* ws = (char*)d_ws;
    float* d_d              = (float*)(ws);                    // 384000 B
    float* d_rhat           = (float*)(ws + 384000);           // 1536000 B
    unsigned short* wbf     = (unsigned short*)(ws + 1920000); // 2260992 B
    unsigned short* d_x     = (unsigned short*)(ws + 4180992); // 3072000 B
    unsigned short* d_xjxi  = (unsigned short*)(ws + 7252992); // 1536000 B
    unsigned short* d_eproj = (unsigned short*)(ws + 8788992); // 36864000 B
    unsigned short* d_xn    = (unsigned short*)(ws + 45652992);// 768000 B
    float* out = (float*)d_out;

    unsigned short* wsrc_bf  = wbf + WSRC_OFF;
    unsigned short* wdst_bf  = wbf + WDST_OFF;
    unsigned short* wedge_bf = wbf + WEDGE_OFF;
    unsigned short* w1_bf    = wbf + W1_OFF;
    unsigned short* w2_bf    = wbf + W2_OFF;

    prep_kernel<<<CVT_BLOCKS + N_NODES + GEOM_BLOCKS, 256, 0, stream>>>(
        Wsrc, Wdst, Wedge, W1, W2, wbf, an, emb, d_x, r, d_d, d_rhat, out, bfc);
    // eproj for all 3 layers: [E,192] = RBF(d) @ Wedge^T + bedge
    mgemm<0,1,0,128><<<dim3(3,750), 256, 0, stream>>>(
        (const unsigned short*)nullptr, 0, wedge_bf, (const unsigned short*)nullptr, 256,
        bedge, (const float*)nullptr, d_eproj, 192, N_EDGES, 256, d_d);

    for (int l = 0; l < 3; ++l) {
        mgemm<0,0,1,64><<<dim3(2,94), 256, 0, stream>>>(
            d_x, 256, wsrc_bf + l*16384, wdst_bf + l*16384, 256,
            bsrc + l*64, bdst + l*64, d_xjxi, 128, N_NODES, 256, nullptr);
        angle_kernel<<<N_NODES, 256, 0, stream>>>(
            d_xjxi, d_eproj + l*64, d_rhat, src, attn + l*64, d_xn);
        ffn_kernel<<<dim3(4,94), 256, 0, stream>>>(
            d_xn, w1_bf + l*65536, b1 + l*D_FF,
            w2_bf + l*262144, b2 + l*D_MODEL, d_x, N_NODES);
    }
    reduce_kernel<<<48, 256, 0, stream>>>(d_x, Wfc, out);
}

// Round 8
// 342.304 us; speedup vs baseline: 5.1897x; 1.4261x over previous
//
#include <hip/hip_runtime.h>

#define N_NODES 6000
#define DEG_    16
#define N_EDGES (N_NODES*DEG_)
#define D_MODEL 256
#define D_MSG   64
#define D_FF    1024

typedef __bf16 bf16x8 __attribute__((ext_vector_type(8)));
typedef float floatx4 __attribute__((ext_vector_type(4)));

__device__ __forceinline__ float silu_f(float v) {
    return v * __builtin_amdgcn_rcpf(1.0f + __expf(-v));
}
__device__ __forceinline__ float b2f(unsigned short u) {
    union { unsigned int i; float f; } v; v.i = ((unsigned int)u) << 16; return v.f;
}
__device__ __forceinline__ unsigned short f2b(float f) {
    union { float f; unsigned int i; } v; v.f = f;
    unsigned int r = (v.i + 0x7FFFu + ((v.i >> 16) & 1u)) >> 16;
    return (unsigned short)r;
}

// ---------------- fused prep: weight cvt + embed + geometry + out init ----------------
#define WSRC_OFF 0
#define WDST_OFF 49152
#define WEDGE_OFF 98304
#define W1_OFF 147456
#define W2_OFF 344064
#define WTOTAL 1130496
#define CVT_BLOCKS ((WTOTAL+255)/256)          // 4416
#define GEOM_BLOCKS (N_EDGES/256)              // 375
__global__ __launch_bounds__(256) void prep_kernel(
    const float* __restrict__ Wsrc, const float* __restrict__ Wdst,
    const float* __restrict__ Wedge, const float* __restrict__ W1,
    const float* __restrict__ W2, unsigned short* __restrict__ wdst_out,
    const int* __restrict__ an, const float* __restrict__ emb,
    unsigned short* __restrict__ x,
    const float* __restrict__ r, float* __restrict__ d, float* __restrict__ rhat,
    float* __restrict__ out, const float* __restrict__ bfc) {
    int b = blockIdx.x;
    int t = threadIdx.x;
    if (b == 0 && t == 0) out[0] = bfc[0];
    if (b < CVT_BLOCKS) {
        int i = b*256 + t;
        if (i < WTOTAL) {
            float v;
            if      (i < WDST_OFF)  v = Wsrc[i];
            else if (i < WEDGE_OFF) v = Wdst[i - WDST_OFF];
            else if (i < W1_OFF)    v = Wedge[i - WEDGE_OFF];
            else if (i < W2_OFF)    v = W1[i - W1_OFF];
            else                    v = W2[i - W2_OFF];
            wdst_out[i] = f2b(v);
        }
    } else if (b < CVT_BLOCKS + N_NODES) {
        int i = b - CVT_BLOCKS;
        x[i*D_MODEL + t] = f2b(emb[an[i]*D_MODEL + t]);
    } else {
        int e = (b - CVT_BLOCKS - N_NODES)*256 + t;
        float xx = r[e*3+0], yy = r[e*3+1], zz = r[e*3+2];
        float n = sqrtf(xx*xx + yy*yy + zz*zz);
        d[e] = n;
        float inv = 1.0f / n;
        *(float4*)(rhat + (size_t)e*4) = make_float4(xx*inv, yy*inv, zz*inv, 0.f);
    }
}

// ---------------- MFMA bf16 GEMM, software-pipelined staging ----------------
// C = bf16(act(A @ B^T + bias)); block tile TM x 64; BK=32.
#define APITCH 40
template<int ACT, int RBF, int DUALB, int TM>
__global__ __launch_bounds__(256) void mgemm(
    const unsigned short* __restrict__ A, int lda,
    const unsigned short* __restrict__ B1, const unsigned short* __restrict__ B2, int ldb,
    const float* __restrict__ bias1, const float* __restrict__ bias2,
    unsigned short* __restrict__ C, int ldc, int M, int K,
    const float* __restrict__ dvec) {
    constexpr int WR = TM/4;
    constexpr int FC = WR/16;
    constexpr int NIT = TM/64;
    __shared__ __align__(16) unsigned short As[TM*APITCH];
    __shared__ __align__(16) unsigned short Bs[64*APITCH];
    const int t = threadIdx.x;
    const int w = t >> 6;
    const int lane = t & 63;
    const int lr = lane & 15;
    const int lq = lane >> 4;
    const int n0 = blockIdx.x * 64;
    const int m0 = blockIdx.y * TM;
    const unsigned short* B = B1;
    const float* bias = bias1;
    if (DUALB && blockIdx.x == 1) { B = B2; bias = bias2; }
    const unsigned short* Brow = DUALB ? B : (B + (size_t)n0*ldb);

    int arow[NIT], achk[NIT];
    #pragma unroll
    for (int it = 0; it < NIT; ++it) { int i = t + it*256; arow[it] = i >> 2; achk[it] = i & 3; }
    const int brow = t >> 2, bchk = t & 3;

    floatx4 acc[FC][4] = {};
    uint4 pa[NIT], pb;

    // prologue: fetch k0=0
    #pragma unroll
    for (int it = 0; it < NIT; ++it) {
        int gm = m0 + arow[it];
        if (RBF) {
            const float gamma = 31.875f;
            const float step  = 8.0f / 255.0f;
            float dv = dvec[gm];
            int kb = achk[it]*8;
            unsigned short h[8];
            #pragma unroll
            for (int j = 0; j < 8; ++j) { float tt = dv - (float)(kb+j)*step; h[j] = f2b(__expf(-gamma*tt*tt)); }
            pa[it] = *(uint4*)h;
        } else {
            pa[it] = (gm < M) ? *(const uint4*)(A + (size_t)gm*lda + achk[it]*8) : make_uint4(0,0,0,0);
        }
    }
    pb = *(const uint4*)(Brow + (size_t)brow*ldb + bchk*8);

    for (int k0 = 0; k0 < K; k0 += 32) {
        #pragma unroll
        for (int it = 0; it < NIT; ++it)
            *(uint4*)(&As[arow[it]*APITCH + achk[it]*8]) = pa[it];
        *(uint4*)(&Bs[brow*APITCH + bchk*8]) = pb;
        __syncthreads();
        if (k0 + 32 < K) {              // prefetch next chunk (overlaps MFMA phase)
            int kn = k0 + 32;
            #pragma unroll
            for (int it = 0; it < NIT; ++it) {
                int gm = m0 + arow[it];
                if (RBF) {
                    const float gamma = 31.875f;
                    const float step  = 8.0f / 255.0f;
                    float dv = dvec[gm];
                    int kb = kn + achk[it]*8;
                    unsigned short h[8];
                    #pragma unroll
                    for (int j = 0; j < 8; ++j) { float tt = dv - (float)(kb+j)*step; h[j] = f2b(__expf(-gamma*tt*tt)); }
                    pa[it] = *(uint4*)h;
                } else {
                    pa[it] = (gm < M) ? *(const uint4*)(A + (size_t)gm*lda + kn + achk[it]*8) : make_uint4(0,0,0,0);
                }
            }
            pb = *(const uint4*)(Brow + (size_t)brow*ldb + kn + bchk*8);
        }
        bf16x8 af[FC], bfr[4];
        #pragma unroll
        for (int fc = 0; fc < FC; ++fc)
            af[fc] = *(const bf16x8*)(&As[(w*WR + fc*16 + lr)*APITCH + lq*8]);
        #pragma unroll
        for (int ns = 0; ns < 4; ++ns)
            bfr[ns] = *(const bf16x8*)(&Bs[(ns*16 + lr)*APITCH + lq*8]);
        #pragma unroll
        for (int ns = 0; ns < 4; ++ns)
            #pragma unroll
            for (int fc = 0; fc < FC; ++fc)
                acc[fc][ns] = __builtin_amdgcn_mfma_f32_16x16x32_bf16(af[fc], bfr[ns], acc[fc][ns], 0,0,0);
        __syncthreads();
    }
    #pragma unroll
    for (int ns = 0; ns < 4; ++ns) {
        int bc = ns*16 + lr;
        float bv = bias[DUALB ? bc : (n0 + bc)];
        #pragma unroll
        for (int fc = 0; fc < FC; ++fc) {
            #pragma unroll
            for (int rg = 0; rg < 4; ++rg) {
                int gm = m0 + w*WR + fc*16 + lq*4 + rg;
                if (gm < M) {
                    float v = acc[fc][ns][rg] + bv;
                    if (ACT) v = silu_f(v);
                    C[(size_t)gm*ldc + n0 + bc] = f2b(v);
                }
            }
        }
    }
}

// ---------------- angle attention, one block per node ----------------
// logit[p][q] is SYMMETRIC (T_k(c) sym, xij[p]+xij[q] sym, silu elementwise):
// compute only 120 unique pairs. w_p computed without materializing a[p][q].
#define XSTRIDE 68
__global__ __launch_bounds__(256) void angle_kernel(
    const unsigned short* __restrict__ xjxi,   // [N,128] bf16: 0..63 xj, 64..127 xi
    const unsigned short* __restrict__ eproj,  // [E,192] bf16, pre-offset by l*64
    const float* __restrict__ rhat,            // [E,4]
    const int*   __restrict__ src,             // [E]
    const float* __restrict__ attn,            // [64] pre-offset, wave-uniform
    unsigned short* __restrict__ xn) {         // [N,64] bf16
    __shared__ __align__(16) float s_xij[16][XSTRIDE];
    __shared__ float s_rhat[16][4];
    __shared__ float s_logit[16][17];
    __shared__ float s_m[16], s_zi[16];
    __shared__ float s_w[16];
    int node = blockIdx.x;
    int t = threadIdx.x;

    if (t < 16) {
        float4 rv = *(const float4*)(rhat + (size_t)(node*DEG_ + t)*4);
        s_rhat[t][0] = rv.x; s_rhat[t][1] = rv.y; s_rhat[t][2] = rv.z; s_rhat[t][3] = 0.f;
    }
    if (t < 128) {
        int p = t >> 3, c8 = t & 7;
        int e = node*DEG_ + p;
        int se = src[e];
        uint4 aj = *(const uint4*)(xjxi + (size_t)se*128 + c8*8);
        uint4 ai = *(const uint4*)(xjxi + (size_t)node*128 + 64 + c8*8);
        uint4 ae = *(const uint4*)(eproj + (size_t)e*192 + c8*8);
        const unsigned short* pj = (const unsigned short*)&aj;
        const unsigned short* pi = (const unsigned short*)&ai;
        const unsigned short* pe = (const unsigned short*)&ae;
        #pragma unroll
        for (int j = 0; j < 8; ++j)
            s_xij[p][c8*8 + j] = b2f(pj[j]) + b2f(pi[j]) + b2f(pe[j]);
    }
    __syncthreads();
    if (t < 120) {                 // unique pair p>q: t = p(p-1)/2 + q
        int p = (int)((1.0f + sqrtf(8.0f*(float)t + 1.0f)) * 0.5f);
        int q = t - ((p*(p-1)) >> 1);
        float c = s_rhat[p][0]*s_rhat[q][0] + s_rhat[p][1]*s_rhat[q][1] + s_rhat[p][2]*s_rhat[q][2];
        c = fminf(fmaxf(c, -0.999999f), 0.999999f);
        float c2  = 2.0f * c;
        float tk0 = 1.0f;
        float tk1 = c;
        float acc = 0.f;
        const float* xp = &s_xij[p][0];
        const float* xq = &s_xij[q][0];
        #pragma unroll
        for (int k0 = 0; k0 < 64; k0 += 4) {
            float4 xp4 = *(const float4*)(xp + k0);
            float4 xq4 = *(const float4*)(xq + k0);
            float a0 = attn[k0+0], a1 = attn[k0+1], a2 = attn[k0+2], a3 = attn[k0+3];
            float v0 = tk0 + xp4.x + xq4.x;
            acc = fmaf(a0, silu_f(v0), acc);
            { float tn2 = c2*tk1 - tk0; tk0 = tk1; tk1 = tn2; }
            float v1 = tk0 + xp4.y + xq4.y;
            acc = fmaf(a1, silu_f(v1), acc);
            { float tn2 = c2*tk1 - tk0; tk0 = tk1; tk1 = tn2; }
            float v2 = tk0 + xp4.z + xq4.z;
            acc = fmaf(a2, silu_f(v2), acc);
            { float tn2 = c2*tk1 - tk0; tk0 = tk1; tk1 = tn2; }
            float v3 = tk0 + xp4.w + xq4.w;
            acc = fmaf(a3, silu_f(v3), acc);
            { float tn2 = c2*tk1 - tk0; tk0 = tk1; tk1 = tn2; }
        }
        s_logit[p][q] = acc;
        s_logit[q][p] = acc;
    }
    __syncthreads();
    if (t < 16) {                  // per-column q: max and 1/Z
        int q = t;
        float mx = -1e30f;
        #pragma unroll
        for (int p = 0; p < 16; ++p) if (p != q) mx = fmaxf(mx, s_logit[p][q]);
        float z = 0.f;
        #pragma unroll
        for (int p = 0; p < 16; ++p) if (p != q) z += __expf(s_logit[p][q] - mx);
        s_m[q] = mx;
        s_zi[q] = __builtin_amdgcn_rcpf(z);
    }
    __syncthreads();
    if (t < 16) {                  // w_p = sum_q a[p][q]
        int p = t;
        float sw = 0.f;
        #pragma unroll
        for (int q = 0; q < 16; ++q)
            if (q != p) sw += __expf(s_logit[p][q] - s_m[q]) * s_zi[q];
        s_w[p] = sw;
    }
    __syncthreads();
    if (t < 64) {
        float acc = 0.f;
        #pragma unroll
        for (int p = 0; p < 16; ++p) acc += s_w[p] * s_xij[p][t];
        xn[(size_t)node*64 + t] = f2b(acc);
    }
}

// ---------------- final: out += mean_i (x[i] . Wfc) ----------------
__global__ __launch_bounds__(256) void reduce_kernel(const unsigned short* __restrict__ x,
    const float* __restrict__ Wfc, float* __restrict__ out) {
    __shared__ float s[256];
    int t = threadIdx.x;
    float local = 0.f;
    for (int i = blockIdx.x; i < N_NODES; i += gridDim.x) local += b2f(x[(size_t)i*D_MODEL + t]);
    local *= Wfc[t];
    s[t] = local; __syncthreads();
    for (int off = 128; off > 0; off >>= 1) {
        if (t < off) s[t] += s[t+off];
        __syncthreads();
    }
    if (t == 0) atomicAdd(out, s[0] * (1.0f/(float)N_NODES));
}

extern "C" void kernel_launch(void* const* d_in, const int* in_sizes, int n_in,
                              void* d_out, int out_size, void* d_ws, size_t ws_size,
                              hipStream_t stream) {
    (void)in_sizes; (void)n_in; (void)out_size; (void)ws_size;
    const float* r    = (const float*)d_in[0];
    const int*   an   = (const int*)  d_in[1];
    const int*   src  = (const int*)  d_in[2];
    const float* emb  = (const float*)d_in[6];
    const float* Wsrc = (const float*)d_in[7];
    const float* bsrc = (const float*)d_in[8];
    const float* Wdst = (const float*)d_in[9];
    const float* bdst = (const float*)d_in[10];
    const float* Wedge= (const float*)d_in[11];
    const float* bedge= (const float*)d_in[12];
    const float* attn = (const float*)d_in[13];
    const float* W1   = (const float*)d_in[14];
    const float* b1   = (const float*)d_in[15];
    const float* W2   = (const float*)d_in[16];
    const float* b2   = (const float*)d_in[17];
    const float* Wfc  = (const float*)d_in[18];
    const float* bfc  = (const float*)d_in[19];

    char* ws = (char*)d_ws;
    float* d_d              = (float*)(ws);                    // 384000 B
    float* d_rhat           = (float*)(ws + 384000);           // 1536000 B
    unsigned short* wbf     = (unsigned short*)(ws + 1920000); // 2260992 B
    unsigned short* d_x     = (unsigned short*)(ws + 4180992); // 3072000 B
    unsigned short* d_xjxi  = (unsigned short*)(ws + 7252992); // 1536000 B
    unsigned short* d_eproj = (unsigned short*)(ws + 8788992); // 36864000 B
    unsigned short* d_xn    = (unsigned short*)(ws + 45652992);// 768000 B
    unsigned short* d_h     = (unsigned short*)(ws + 46420992);// 12288000 B
    float* out = (float*)d_out;

    unsigned short* wsrc_bf  = wbf + WSRC_OFF;
    unsigned short* wdst_bf  = wbf + WDST_OFF;
    unsigned short* wedge_bf = wbf + WEDGE_OFF;
    unsigned short* w1_bf    = wbf + W1_OFF;
    unsigned short* w2_bf    = wbf + W2_OFF;

    prep_kernel<<<CVT_BLOCKS + N_NODES + GEOM_BLOCKS, 256, 0, stream>>>(
        Wsrc, Wdst, Wedge, W1, W2, wbf, an, emb, d_x, r, d_d, d_rhat, out, bfc);
    // eproj for all 3 layers: [E,192] = RBF(d) @ Wedge^T + bedge
    mgemm<0,1,0,128><<<dim3(3,750), 256, 0, stream>>>(
        (const unsigned short*)nullptr, 0, wedge_bf, (const unsigned short*)nullptr, 256,
        bedge, (const float*)nullptr, d_eproj, 192, N_EDGES, 256, d_d);

    for (int l = 0; l < 3; ++l) {
        mgemm<0,0,1,64><<<dim3(2,94), 256, 0, stream>>>(
            d_x, 256, wsrc_bf + l*16384, wdst_bf + l*16384, 256,
            bsrc + l*64, bdst + l*64, d_xjxi, 128, N_NODES, 256, nullptr);
        angle_kernel<<<N_NODES, 256, 0, stream>>>(
            d_xjxi, d_eproj + l*64, d_rhat, src, attn + l*64, d_xn);
        mgemm<1,0,0,64><<<dim3(16,94), 256, 0, stream>>>(
            d_xn, 64, w1_bf + l*65536, (const unsigned short*)nullptr, 64,
            b1 + l*D_FF, (const float*)nullptr, d_h, D_FF, N_NODES, 64, nullptr);
        mgemm<0,0,0,64><<<dim3(4,94), 256, 0, stream>>>(
            d_h, 1024, w2_bf + l*262144, (const unsigned short*)nullptr, 1024,
            b2 + l*D_MODEL, (const float*)nullptr, d_x, D_MODEL, N_NODES, 1024, nullptr);
    }
    reduce_kernel<<<48, 256, 0, stream>>>(d_x, Wfc, out);
}

// Round 9
// 333.705 us; speedup vs baseline: 5.3234x; 1.0258x over previous
//
#include <hip/hip_runtime.h>

#define N_NODES 6000
#define DEG_    16
#define N_EDGES (N_NODES*DEG_)
#define D_MODEL 256
#define D_MSG   64
#define D_FF    1024

typedef __bf16 bf16x8 __attribute__((ext_vector_type(8)));
typedef float floatx4 __attribute__((ext_vector_type(4)));

__device__ __forceinline__ float silu_f(float v) {
    return v * __builtin_amdgcn_rcpf(1.0f + __expf(-v));
}
__device__ __forceinline__ float b2f(unsigned short u) {
    union { unsigned int i; float f; } v; v.i = ((unsigned int)u) << 16; return v.f;
}
__device__ __forceinline__ unsigned short f2b(float f) {
    union { float f; unsigned int i; } v; v.f = f;
    unsigned int r = (v.i + 0x7FFFu + ((v.i >> 16) & 1u)) >> 16;
    return (unsigned short)r;
}

// ---------------- fused prep: weight cvt + embed + geometry + out init ----------------
#define WSRC_OFF 0
#define WDST_OFF 49152
#define WEDGE_OFF 98304
#define W1_OFF 147456
#define W2_OFF 344064
#define WTOTAL 1130496
#define CVT_BLOCKS ((WTOTAL+255)/256)          // 4416
#define GEOM_BLOCKS (N_EDGES/256)              // 375
__global__ __launch_bounds__(256) void prep_kernel(
    const float* __restrict__ Wsrc, const float* __restrict__ Wdst,
    const float* __restrict__ Wedge, const float* __restrict__ W1,
    const float* __restrict__ W2, unsigned short* __restrict__ wdst_out,
    const int* __restrict__ an, const float* __restrict__ emb,
    unsigned short* __restrict__ x,
    const float* __restrict__ r, float* __restrict__ d, float* __restrict__ rhat,
    float* __restrict__ out, const float* __restrict__ bfc) {
    int b = blockIdx.x;
    int t = threadIdx.x;
    if (b == 0 && t == 0) out[0] = bfc[0];
    if (b < CVT_BLOCKS) {
        int i = b*256 + t;
        if (i < WTOTAL) {
            float v;
            if      (i < WDST_OFF)  v = Wsrc[i];
            else if (i < WEDGE_OFF) v = Wdst[i - WDST_OFF];
            else if (i < W1_OFF)    v = Wedge[i - WEDGE_OFF];
            else if (i < W2_OFF)    v = W1[i - W1_OFF];
            else                    v = W2[i - W2_OFF];
            wdst_out[i] = f2b(v);
        }
    } else if (b < CVT_BLOCKS + N_NODES) {
        int i = b - CVT_BLOCKS;
        x[i*D_MODEL + t] = f2b(emb[an[i]*D_MODEL + t]);
    } else {
        int e = (b - CVT_BLOCKS - N_NODES)*256 + t;
        float xx = r[e*3+0], yy = r[e*3+1], zz = r[e*3+2];
        float n = sqrtf(xx*xx + yy*yy + zz*zz);
        d[e] = n;
        float inv = 1.0f / n;
        *(float4*)(rhat + (size_t)e*4) = make_float4(xx*inv, yy*inv, zz*inv, 0.f);
    }
}

// ---------------- eproj: [E,192] = RBF(d) @ Wedge^T + bedge, single pass ----------------
// TM=128 x TN=192, BK=32, grid 750. RBF A-tile generated ONCE per k-iter,
// multiplied against all 192 Wedge rows (24 MFMA/wave/iter).
#define EPITCH 40
__global__ __launch_bounds__(256) void eproj_kernel(
    const unsigned short* __restrict__ Bw,  // [192,256] bf16 (3 layers stacked)
    const float* __restrict__ bias,         // [192]
    const float* __restrict__ dvec,         // [E]
    unsigned short* __restrict__ C) {       // [E,192]
    __shared__ __align__(16) unsigned short As[128*EPITCH];
    __shared__ __align__(16) unsigned short Bs[192*EPITCH];
    const int t = threadIdx.x;
    const int w = t >> 6, lane = t & 63, lr = lane & 15, lq = lane >> 4;
    const int m0 = blockIdx.x * 128;

    int arow[2], achk[2], brow[3], bchk[3];
    #pragma unroll
    for (int it = 0; it < 2; ++it) { int i = t + it*256; arow[it] = i >> 2; achk[it] = i & 3; }
    #pragma unroll
    for (int it = 0; it < 3; ++it) { int i = t + it*256; brow[it] = i >> 2; bchk[it] = i & 3; }

    float dv[2];
    dv[0] = dvec[m0 + arow[0]];
    dv[1] = dvec[m0 + arow[1]];

    floatx4 acc[2][12] = {};
    uint4 pb[3];
    #pragma unroll
    for (int it = 0; it < 3; ++it)
        pb[it] = *(const uint4*)(Bw + (size_t)brow[it]*256 + bchk[it]*8);

    const float gamma = 31.875f;
    const float step  = 8.0f / 255.0f;
    for (int k0 = 0; k0 < 256; k0 += 32) {
        #pragma unroll
        for (int it = 0; it < 2; ++it) {
            int kb = k0 + achk[it]*8;
            unsigned short h[8];
            #pragma unroll
            for (int j = 0; j < 8; ++j) {
                float tt = dv[it] - (float)(kb+j)*step;
                h[j] = f2b(__expf(-gamma*tt*tt));
            }
            *(uint4*)(&As[arow[it]*EPITCH + achk[it]*8]) = *(uint4*)h;
        }
        #pragma unroll
        for (int it = 0; it < 3; ++it)
            *(uint4*)(&Bs[brow[it]*EPITCH + bchk[it]*8]) = pb[it];
        __syncthreads();
        if (k0 + 32 < 256) {
            #pragma unroll
            for (int it = 0; it < 3; ++it)
                pb[it] = *(const uint4*)(Bw + (size_t)brow[it]*256 + (k0+32) + bchk[it]*8);
        }
        bf16x8 af0 = *(const bf16x8*)(&As[(w*32      + lr)*EPITCH + lq*8]);
        bf16x8 af1 = *(const bf16x8*)(&As[(w*32 + 16 + lr)*EPITCH + lq*8]);
        #pragma unroll
        for (int ns = 0; ns < 12; ++ns) {
            bf16x8 b = *(const bf16x8*)(&Bs[(ns*16 + lr)*EPITCH + lq*8]);
            acc[0][ns] = __builtin_amdgcn_mfma_f32_16x16x32_bf16(af0, b, acc[0][ns], 0,0,0);
            acc[1][ns] = __builtin_amdgcn_mfma_f32_16x16x32_bf16(af1, b, acc[1][ns], 0,0,0);
        }
        __syncthreads();
    }
    #pragma unroll
    for (int ns = 0; ns < 12; ++ns) {
        int bc = ns*16 + lr;
        float bv = bias[bc];
        #pragma unroll
        for (int fc = 0; fc < 2; ++fc) {
            #pragma unroll
            for (int rg = 0; rg < 4; ++rg) {
                int gm = m0 + w*32 + fc*16 + lq*4 + rg;
                C[(size_t)gm*192 + bc] = f2b(acc[fc][ns][rg] + bv);
            }
        }
    }
}

// ---------------- MFMA bf16 GEMM, software-pipelined staging ----------------
#define APITCH 40
template<int ACT, int DUALB, int TM>
__global__ __launch_bounds__(256) void mgemm(
    const unsigned short* __restrict__ A, int lda,
    const unsigned short* __restrict__ B1, const unsigned short* __restrict__ B2, int ldb,
    const float* __restrict__ bias1, const float* __restrict__ bias2,
    unsigned short* __restrict__ C, int ldc, int M, int K) {
    constexpr int WR = TM/4;
    constexpr int FC = WR/16;
    constexpr int NIT = TM/64;
    __shared__ __align__(16) unsigned short As[TM*APITCH];
    __shared__ __align__(16) unsigned short Bs[64*APITCH];
    const int t = threadIdx.x;
    const int w = t >> 6;
    const int lane = t & 63;
    const int lr = lane & 15;
    const int lq = lane >> 4;
    const int n0 = blockIdx.x * 64;
    const int m0 = blockIdx.y * TM;
    const unsigned short* B = B1;
    const float* bias = bias1;
    if (DUALB && blockIdx.x == 1) { B = B2; bias = bias2; }
    const unsigned short* Brow = DUALB ? B : (B + (size_t)n0*ldb);

    int arow[NIT], achk[NIT];
    #pragma unroll
    for (int it = 0; it < NIT; ++it) { int i = t + it*256; arow[it] = i >> 2; achk[it] = i & 3; }
    const int brow = t >> 2, bchk = t & 3;

    floatx4 acc[FC][4] = {};
    uint4 pa[NIT], pb;

    #pragma unroll
    for (int it = 0; it < NIT; ++it) {
        int gm = m0 + arow[it];
        pa[it] = (gm < M) ? *(const uint4*)(A + (size_t)gm*lda + achk[it]*8) : make_uint4(0,0,0,0);
    }
    pb = *(const uint4*)(Brow + (size_t)brow*ldb + bchk*8);

    for (int k0 = 0; k0 < K; k0 += 32) {
        #pragma unroll
        for (int it = 0; it < NIT; ++it)
            *(uint4*)(&As[arow[it]*APITCH + achk[it]*8]) = pa[it];
        *(uint4*)(&Bs[brow*APITCH + bchk*8]) = pb;
        __syncthreads();
        if (k0 + 32 < K) {
            int kn = k0 + 32;
            #pragma unroll
            for (int it = 0; it < NIT; ++it) {
                int gm = m0 + arow[it];
                pa[it] = (gm < M) ? *(const uint4*)(A + (size_t)gm*lda + kn + achk[it]*8) : make_uint4(0,0,0,0);
            }
            pb = *(const uint4*)(Brow + (size_t)brow*ldb + kn + bchk*8);
        }
        bf16x8 af[FC], bfr[4];
        #pragma unroll
        for (int fc = 0; fc < FC; ++fc)
            af[fc] = *(const bf16x8*)(&As[(w*WR + fc*16 + lr)*APITCH + lq*8]);
        #pragma unroll
        for (int ns = 0; ns < 4; ++ns)
            bfr[ns] = *(const bf16x8*)(&Bs[(ns*16 + lr)*APITCH + lq*8]);
        #pragma unroll
        for (int ns = 0; ns < 4; ++ns)
            #pragma unroll
            for (int fc = 0; fc < FC; ++fc)
                acc[fc][ns] = __builtin_amdgcn_mfma_f32_16x16x32_bf16(af[fc], bfr[ns], acc[fc][ns], 0,0,0);
        __syncthreads();
    }
    #pragma unroll
    for (int ns = 0; ns < 4; ++ns) {
        int bc = ns*16 + lr;
        float bv = bias[DUALB ? bc : (n0 + bc)];
        #pragma unroll
        for (int fc = 0; fc < FC; ++fc) {
            #pragma unroll
            for (int rg = 0; rg < 4; ++rg) {
                int gm = m0 + w*WR + fc*16 + lq*4 + rg;
                if (gm < M) {
                    float v = acc[fc][ns][rg] + bv;
                    if (ACT) v = silu_f(v);
                    C[(size_t)gm*ldc + n0 + bc] = f2b(v);
                }
            }
        }
    }
}

// ---------------- angle attention, TWO nodes per block ----------------
// Half h = t>>7 handles node blockIdx.x*2+h. Pair phase: 240/256 threads busy.
// logit symmetric -> 120 unique pairs per node.
__global__ __launch_bounds__(256) void angle_kernel(
    const unsigned short* __restrict__ xjxi,   // [N,128] bf16: 0..63 xj, 64..127 xi
    const unsigned short* __restrict__ eproj,  // [E,192] bf16, pre-offset by l*64
    const float* __restrict__ rhat,            // [E,4]
    const int*   __restrict__ src,             // [E]
    const float* __restrict__ attn,            // [64] pre-offset, wave-uniform
    unsigned short* __restrict__ xn) {         // [N,64] bf16
    __shared__ __align__(16) float s_xij[2][16][68];
    __shared__ float s_rhat[2][16][4];
    __shared__ float s_logit[2][16][17];
    __shared__ float s_m[2][16], s_zi[2][16];
    __shared__ float s_w[2][16];
    const int t = threadIdx.x;
    const int h = t >> 7, tt = t & 127;
    const int node = blockIdx.x*2 + h;

    if (tt < 16) {
        float4 rv = *(const float4*)(rhat + (size_t)(node*DEG_ + tt)*4);
        s_rhat[h][tt][0] = rv.x; s_rhat[h][tt][1] = rv.y; s_rhat[h][tt][2] = rv.z; s_rhat[h][tt][3] = 0.f;
    }
    {
        int p = tt >> 3, c8 = tt & 7;
        int e = node*DEG_ + p;
        int se = src[e];
        uint4 aj = *(const uint4*)(xjxi + (size_t)se*128 + c8*8);
        uint4 ai = *(const uint4*)(xjxi + (size_t)node*128 + 64 + c8*8);
        uint4 ae = *(const uint4*)(eproj + (size_t)e*192 + c8*8);
        const unsigned short* pj = (const unsigned short*)&aj;
        const unsigned short* pi = (const unsigned short*)&ai;
        const unsigned short* pe = (const unsigned short*)&ae;
        #pragma unroll
        for (int j = 0; j < 8; ++j)
            s_xij[h][p][c8*8 + j] = b2f(pj[j]) + b2f(pi[j]) + b2f(pe[j]);
    }
    __syncthreads();
    if (tt < 120) {                 // unique pair p>q: tt = p(p-1)/2 + q
        int p = (int)((1.0f + sqrtf(8.0f*(float)tt + 1.0f)) * 0.5f);
        int q = tt - ((p*(p-1)) >> 1);
        float c = s_rhat[h][p][0]*s_rhat[h][q][0] + s_rhat[h][p][1]*s_rhat[h][q][1]
                + s_rhat[h][p][2]*s_rhat[h][q][2];
        c = fminf(fmaxf(c, -0.999999f), 0.999999f);
        float c2  = 2.0f * c;
        float tk0 = 1.0f;
        float tk1 = c;
        float acc = 0.f;
        const float* xp = &s_xij[h][p][0];
        const float* xq = &s_xij[h][q][0];
        #pragma unroll
        for (int k0 = 0; k0 < 64; k0 += 4) {
            float4 xp4 = *(const float4*)(xp + k0);
            float4 xq4 = *(const float4*)(xq + k0);
            float a0 = attn[k0+0], a1 = attn[k0+1], a2 = attn[k0+2], a3 = attn[k0+3];
            float v0 = tk0 + xp4.x + xq4.x;
            acc = fmaf(a0, silu_f(v0), acc);
            { float tn2 = c2*tk1 - tk0; tk0 = tk1; tk1 = tn2; }
            float v1 = tk0 + xp4.y + xq4.y;
            acc = fmaf(a1, silu_f(v1), acc);
            { float tn2 = c2*tk1 - tk0; tk0 = tk1; tk1 = tn2; }
            float v2 = tk0 + xp4.z + xq4.z;
            acc = fmaf(a2, silu_f(v2), acc);
            { float tn2 = c2*tk1 - tk0; tk0 = tk1; tk1 = tn2; }
            float v3 = tk0 + xp4.w + xq4.w;
            acc = fmaf(a3, silu_f(v3), acc);
            { float tn2 = c2*tk1 - tk0; tk0 = tk1; tk1 = tn2; }
        }
        s_logit[h][p][q] = acc;
        s_logit[h][q][p] = acc;
    }
    __syncthreads();
    if (tt < 16) {                  // per-column q: max and 1/Z
        int q = tt;
        float mx = -1e30f;
        #pragma unroll
        for (int p = 0; p < 16; ++p) if (p != q) mx = fmaxf(mx, s_logit[h][p][q]);
        float z = 0.f;
        #pragma unroll
        for (int p = 0; p < 16; ++p) if (p != q) z += __expf(s_logit[h][p][q] - mx);
        s_m[h][q] = mx;
        s_zi[h][q] = __builtin_amdgcn_rcpf(z);
    }
    __syncthreads();
    if (tt < 16) {                  // w_p = sum_q a[p][q]
        int p = tt;
        float sw = 0.f;
        #pragma unroll
        for (int q = 0; q < 16; ++q)
            if (q != p) sw += __expf(s_logit[h][p][q] - s_m[h][q]) * s_zi[h][q];
        s_w[h][p] = sw;
    }
    __syncthreads();
    if (tt < 64) {
        float acc = 0.f;
        #pragma unroll
        for (int p = 0; p < 16; ++p) acc += s_w[h][p] * s_xij[h][p][tt];
        xn[(size_t)node*64 + tt] = f2b(acc);
    }
}

// ---------------- final: out += mean_i (x[i] . Wfc) ----------------
__global__ __launch_bounds__(256) void reduce_kernel(const unsigned short* __restrict__ x,
    const float* __restrict__ Wfc, float* __restrict__ out) {
    __shared__ float s[256];
    int t = threadIdx.x;
    float local = 0.f;
    for (int i = blockIdx.x; i < N_NODES; i += gridDim.x) local += b2f(x[(size_t)i*D_MODEL + t]);
    local *= Wfc[t];
    s[t] = local; __syncthreads();
    for (int off = 128; off > 0; off >>= 1) {
        if (t < off) s[t] += s[t+off];
        __syncthreads();
    }
    if (t == 0) atomicAdd(out, s[0] * (1.0f/(float)N_NODES));
}

extern "C" void kernel_launch(void* const* d_in, const int* in_sizes, int n_in,
                              void* d_out, int out_size, void* d_ws, size_t ws_size,
                              hipStream_t stream) {
    (void)in_sizes; (void)n_in; (void)out_size; (void)ws_size;
    const float* r    = (const float*)d_in[0];
    const int*   an   = (const int*)  d_in[1];
    const int*   src  = (const int*)  d_in[2];
    const float* emb  = (const float*)d_in[6];
    const float* Wsrc = (const float*)d_in[7];
    const float* bsrc = (const float*)d_in[8];
    const float* Wdst = (const float*)d_in[9];
    const float* bdst = (const float*)d_in[10];
    const float* Wedge= (const float*)d_in[11];
    const float* bedge= (const float*)d_in[12];
    const float* attn = (const float*)d_in[13];
    const float* W1   = (const float*)d_in[14];
    const float* b1   = (const float*)d_in[15];
    const float* W2   = (const float*)d_in[16];
    const float* b2   = (const float*)d_in[17];
    const float* Wfc  = (const float*)d_in[18];
    const float* bfc  = (const float*)d_in[19];

    char* ws = (char*)d_ws;
    float* d_d              = (float*)(ws);                    // 384000 B
    float* d_rhat           = (float*)(ws + 384000);           // 1536000 B
    unsigned short* wbf     = (unsigned short*)(ws + 1920000); // 2260992 B
    unsigned short* d_x     = (unsigned short*)(ws + 4180992); // 3072000 B
    unsigned short* d_xjxi  = (unsigned short*)(ws + 7252992); // 1536000 B
    unsigned short* d_eproj = (unsigned short*)(ws + 8788992); // 36864000 B
    unsigned short* d_xn    = (unsigned short*)(ws + 45652992);// 768000 B
    unsigned short* d_h     = (unsigned short*)(ws + 46420992);// 12288000 B
    float* out = (float*)d_out;

    unsigned short* wsrc_bf  = wbf + WSRC_OFF;
    unsigned short* wdst_bf  = wbf + WDST_OFF;
    unsigned short* wedge_bf = wbf + WEDGE_OFF;
    unsigned short* w1_bf    = wbf + W1_OFF;
    unsigned short* w2_bf    = wbf + W2_OFF;

    prep_kernel<<<CVT_BLOCKS + N_NODES + GEOM_BLOCKS, 256, 0, stream>>>(
        Wsrc, Wdst, Wedge, W1, W2, wbf, an, emb, d_x, r, d_d, d_rhat, out, bfc);
    // eproj for all 3 layers in one pass: [E,192] = RBF(d) @ Wedge^T + bedge
    eproj_kernel<<<750, 256, 0, stream>>>(wedge_bf, bedge, d_d, d_eproj);

    for (int l = 0; l < 3; ++l) {
        mgemm<0,1,64><<<dim3(2,94), 256, 0, stream>>>(
            d_x, 256, wsrc_bf + l*16384, wdst_bf + l*16384, 256,
            bsrc + l*64, bdst + l*64, d_xjxi, 128, N_NODES, 256);
        angle_kernel<<<N_NODES/2, 256, 0, stream>>>(
            d_xjxi, d_eproj + l*64, d_rhat, src, attn + l*64, d_xn);
        mgemm<1,0,64><<<dim3(16,94), 256, 0, stream>>>(
            d_xn, 64, w1_bf + l*65536, (const unsigned short*)nullptr, 64,
            b1 + l*D_FF, (const float*)nullptr, d_h, D_FF, N_NODES, 64);
        mgemm<0,0,64><<<dim3(4,94), 256, 0, stream>>>(
            d_h, 1024, w2_bf + l*262144, (const unsigned short*)nullptr, 1024,
            b2 + l*D_MODEL, (const float*)nullptr, d_x, D_MODEL, N_NODES, 1024);
    }
    reduce_kernel<<<48, 256, 0, stream>>>(d_x, Wfc, out);
}

// Round 11
// 324.968 us; speedup vs baseline: 5.4665x; 1.0269x over previous
//
#include <hip/hip_runtime.h>

#define N_NODES 6000
#define DEG_    16
#define N_EDGES (N_NODES*DEG_)
#define D_MODEL 256
#define D_MSG   64
#define D_FF    1024

typedef __bf16 bf16x8 __attribute__((ext_vector_type(8)));
typedef float floatx4 __attribute__((ext_vector_type(4)));

__device__ __forceinline__ float silu_f(float v) {
    return v * __builtin_amdgcn_rcpf(1.0f + __expf(-v));
}
__device__ __forceinline__ float b2f(unsigned short u) {
    union { unsigned int i; float f; } v; v.i = ((unsigned int)u) << 16; return v.f;
}
__device__ __forceinline__ unsigned short f2b(float f) {
    union { float f; unsigned int i; } v; v.f = f;
    unsigned int r = (v.i + 0x7FFFu + ((v.i >> 16) & 1u)) >> 16;
    return (unsigned short)r;
}
__device__ __forceinline__ unsigned short f2b_t(float f) {  // truncating (RBF only)
    union { float f; unsigned int i; } v; v.f = f;
    return (unsigned short)(v.i >> 16);
}

// ---------------- fused prep (vectorized): weight cvt + embed + geometry ----------------
#define WSRC_OFF 0
#define WDST_OFF 49152
#define WEDGE_OFF 98304
#define W1_OFF 147456
#define W2_OFF 344064
#define WTOTAL 1130496
#define CVT4_BLOCKS (WTOTAL/4/256)             // 1104
#define EMB4_BLOCKS (N_NODES*D_MODEL/4/256)    // 1500
#define GEOM_BLOCKS (N_EDGES/256)              // 375
__global__ __launch_bounds__(256) void prep_kernel(
    const float* __restrict__ Wsrc, const float* __restrict__ Wdst,
    const float* __restrict__ Wedge, const float* __restrict__ W1,
    const float* __restrict__ W2, unsigned short* __restrict__ wdst_out,
    const int* __restrict__ an, const float* __restrict__ emb,
    unsigned short* __restrict__ x,
    const float* __restrict__ r, float* __restrict__ d, float* __restrict__ rhat,
    float* __restrict__ out, const float* __restrict__ bfc) {
    int b = blockIdx.x;
    int t = threadIdx.x;
    if (b == 0 && t == 0) out[0] = bfc[0];
    if (b < CVT4_BLOCKS) {
        int i = (b*256 + t) * 4;
        const float* sp;
        if      (i < WDST_OFF)  sp = Wsrc + i;
        else if (i < WEDGE_OFF) sp = Wdst + (i - WDST_OFF);
        else if (i < W1_OFF)    sp = Wedge + (i - WEDGE_OFF);
        else if (i < W2_OFF)    sp = W1 + (i - W1_OFF);
        else                    sp = W2 + (i - W2_OFF);
        float4 v = *(const float4*)sp;
        *(ushort4*)(wdst_out + i) = make_ushort4(f2b(v.x), f2b(v.y), f2b(v.z), f2b(v.w));
    } else if (b < CVT4_BLOCKS + EMB4_BLOCKS) {
        int i4 = (b - CVT4_BLOCKS)*256 + t;      // float4 index
        int node = i4 >> 6, c4 = i4 & 63;
        float4 v = *(const float4*)(emb + (size_t)an[node]*D_MODEL + c4*4);
        *(ushort4*)(x + (size_t)node*D_MODEL + c4*4) =
            make_ushort4(f2b(v.x), f2b(v.y), f2b(v.z), f2b(v.w));
    } else {
        int e = (b - CVT4_BLOCKS - EMB4_BLOCKS)*256 + t;
        float xx = r[e*3+0], yy = r[e*3+1], zz = r[e*3+2];
        float n = sqrtf(xx*xx + yy*yy + zz*zz);
        d[e] = n;
        float inv = 1.0f / n;
        *(float4*)(rhat + (size_t)e*4) = make_float4(xx*inv, yy*inv, zz*inv, 0.f);
    }
}

// ---------------- eproj: [E,192] = RBF(d) @ Wedge^T + bedge, single pass ----------------
#define EPITCH 40
__global__ __launch_bounds__(256) void eproj_kernel(
    const unsigned short* __restrict__ Bw,  // [192,256] bf16 (3 layers stacked)
    const float* __restrict__ bias,         // [192]
    const float* __restrict__ dvec,         // [E]
    unsigned short* __restrict__ C) {       // [E,192]
    __shared__ __align__(16) unsigned short As[128*EPITCH];
    __shared__ __align__(16) unsigned short Bs[192*EPITCH];
    const int t = threadIdx.x;
    const int w = t >> 6, lane = t & 63, lr = lane & 15, lq = lane >> 4;
    const int m0 = blockIdx.x * 128;

    int arow[2], achk[2], brow[3], bchk[3];
    #pragma unroll
    for (int it = 0; it < 2; ++it) { int i = t + it*256; arow[it] = i >> 2; achk[it] = i & 3; }
    #pragma unroll
    for (int it = 0; it < 3; ++it) { int i = t + it*256; brow[it] = i >> 2; bchk[it] = i & 3; }

    float dv[2];
    dv[0] = dvec[m0 + arow[0]];
    dv[1] = dvec[m0 + arow[1]];

    floatx4 acc[2][12] = {};
    uint4 pb[3];
    #pragma unroll
    for (int it = 0; it < 3; ++it)
        pb[it] = *(const uint4*)(Bw + (size_t)brow[it]*256 + bchk[it]*8);

    const float gamma = 31.875f;
    const float step  = 8.0f / 255.0f;
    for (int k0 = 0; k0 < 256; k0 += 32) {
        #pragma unroll
        for (int it = 0; it < 2; ++it) {
            int kb = k0 + achk[it]*8;
            unsigned short h[8];
            #pragma unroll
            for (int j = 0; j < 8; ++j) {
                float tt = dv[it] - (float)(kb+j)*step;
                h[j] = f2b_t(__expf(-gamma*tt*tt));   // truncating pack: 1 instr
            }
            *(uint4*)(&As[arow[it]*EPITCH + achk[it]*8]) = *(uint4*)h;
        }
        #pragma unroll
        for (int it = 0; it < 3; ++it)
            *(uint4*)(&Bs[brow[it]*EPITCH + bchk[it]*8]) = pb[it];
        __syncthreads();
        if (k0 + 32 < 256) {
            #pragma unroll
            for (int it = 0; it < 3; ++it)
                pb[it] = *(const uint4*)(Bw + (size_t)brow[it]*256 + (k0+32) + bchk[it]*8);
        }
        bf16x8 af0 = *(const bf16x8*)(&As[(w*32      + lr)*EPITCH + lq*8]);
        bf16x8 af1 = *(const bf16x8*)(&As[(w*32 + 16 + lr)*EPITCH + lq*8]);
        #pragma unroll
        for (int ns = 0; ns < 12; ++ns) {
            bf16x8 b = *(const bf16x8*)(&Bs[(ns*16 + lr)*EPITCH + lq*8]);
            acc[0][ns] = __builtin_amdgcn_mfma_f32_16x16x32_bf16(af0, b, acc[0][ns], 0,0,0);
            acc[1][ns] = __builtin_amdgcn_mfma_f32_16x16x32_bf16(af1, b, acc[1][ns], 0,0,0);
        }
        __syncthreads();
    }
    #pragma unroll
    for (int ns = 0; ns < 12; ++ns) {
        int bc = ns*16 + lr;
        float bv = bias[bc];
        #pragma unroll
        for (int fc = 0; fc < 2; ++fc) {
            #pragma unroll
            for (int rg = 0; rg < 4; ++rg) {
                int gm = m0 + w*32 + fc*16 + lq*4 + rg;
                C[(size_t)gm*192 + bc] = f2b(acc[fc][ns][rg] + bv);
            }
        }
    }
}

// ---------------- MFMA bf16 GEMM, software-pipelined staging ----------------
#define APITCH 40
template<int ACT, int DUALB, int TM>
__global__ __launch_bounds__(256) void mgemm(
    const unsigned short* __restrict__ A, int lda,
    const unsigned short* __restrict__ B1, const unsigned short* __restrict__ B2, int ldb,
    const float* __restrict__ bias1, const float* __restrict__ bias2,
    unsigned short* __restrict__ C, int ldc, int M, int K) {
    constexpr int WR = TM/4;
    constexpr int FC = WR/16;
    constexpr int NIT = TM/64;
    __shared__ __align__(16) unsigned short As[TM*APITCH];
    __shared__ __align__(16) unsigned short Bs[64*APITCH];
    const int t = threadIdx.x;
    const int w = t >> 6;
    const int lane = t & 63;
    const int lr = lane & 15;
    const int lq = lane >> 4;
    const int n0 = blockIdx.x * 64;
    const int m0 = blockIdx.y * TM;
    const unsigned short* B = B1;
    const float* bias = bias1;
    if (DUALB && blockIdx.x == 1) { B = B2; bias = bias2; }
    const unsigned short* Brow = DUALB ? B : (B + (size_t)n0*ldb);

    int arow[NIT], achk[NIT];
    #pragma unroll
    for (int it = 0; it < NIT; ++it) { int i = t + it*256; arow[it] = i >> 2; achk[it] = i & 3; }
    const int brow = t >> 2, bchk = t & 3;

    floatx4 acc[FC][4] = {};
    uint4 pa[NIT], pb;

    #pragma unroll
    for (int it = 0; it < NIT; ++it) {
        int gm = m0 + arow[it];
        pa[it] = (gm < M) ? *(const uint4*)(A + (size_t)gm*lda + achk[it]*8) : make_uint4(0,0,0,0);
    }
    pb = *(const uint4*)(Brow + (size_t)brow*ldb + bchk*8);

    for (int k0 = 0; k0 < K; k0 += 32) {
        #pragma unroll
        for (int it = 0; it < NIT; ++it)
            *(uint4*)(&As[arow[it]*APITCH + achk[it]*8]) = pa[it];
        *(uint4*)(&Bs[brow*APITCH + bchk*8]) = pb;
        __syncthreads();
        if (k0 + 32 < K) {
            int kn = k0 + 32;
            #pragma unroll
            for (int it = 0; it < NIT; ++it) {
                int gm = m0 + arow[it];
                pa[it] = (gm < M) ? *(const uint4*)(A + (size_t)gm*lda + kn + achk[it]*8) : make_uint4(0,0,0,0);
            }
            pb = *(const uint4*)(Brow + (size_t)brow*ldb + kn + bchk*8);
        }
        bf16x8 af[FC], bfr[4];
        #pragma unroll
        for (int fc = 0; fc < FC; ++fc)
            af[fc] = *(const bf16x8*)(&As[(w*WR + fc*16 + lr)*APITCH + lq*8]);
        #pragma unroll
        for (int ns = 0; ns < 4; ++ns)
            bfr[ns] = *(const bf16x8*)(&Bs[(ns*16 + lr)*APITCH + lq*8]);
        #pragma unroll
        for (int ns = 0; ns < 4; ++ns)
            #pragma unroll
            for (int fc = 0; fc < FC; ++fc)
                acc[fc][ns] = __builtin_amdgcn_mfma_f32_16x16x32_bf16(af[fc], bfr[ns], acc[fc][ns], 0,0,0);
        __syncthreads();
    }
    #pragma unroll
    for (int ns = 0; ns < 4; ++ns) {
        int bc = ns*16 + lr;
        float bv = bias[DUALB ? bc : (n0 + bc)];
        #pragma unroll
        for (int fc = 0; fc < FC; ++fc) {
            #pragma unroll
            for (int rg = 0; rg < 4; ++rg) {
                int gm = m0 + w*WR + fc*16 + lq*4 + rg;
                if (gm < M) {
                    float v = acc[fc][ns][rg] + bv;
                    if (ACT) v = silu_f(v);
                    C[(size_t)gm*ldc + n0 + bc] = f2b(v);
                }
            }
        }
    }
}

// ---------------- angle attention, TWO nodes per block ----------------
// Symmetric logits -> 120 unique pairs. Softmax WITH max subtraction
// (overflow-safe; R9's no-max variant NaN'd at layer>=2), but the exps are
// computed by the 240 pair threads in parallel (2 exps each), not serially.
__global__ __launch_bounds__(256) void angle_kernel(
    const unsigned short* __restrict__ xjxi,   // [N,128] bf16: 0..63 xj, 64..127 xi
    const unsigned short* __restrict__ eproj,  // [E,192] bf16, pre-offset by l*64
    const float* __restrict__ rhat,            // [E,4]
    const int*   __restrict__ src,             // [E]
    const float* __restrict__ attn,            // [64] pre-offset, wave-uniform
    unsigned short* __restrict__ xn) {         // [N,64] bf16
    __shared__ __align__(16) float s_xij[2][16][68];
    __shared__ float s_rhat[2][16][4];
    __shared__ float s_logit[2][16][17];
    __shared__ float s_e[2][16][17];
    __shared__ float s_m[2][16], s_zi[2][16];
    __shared__ float s_w[2][16];
    const int t = threadIdx.x;
    const int h = t >> 7, tt = t & 127;
    const int node = blockIdx.x*2 + h;

    if (tt < 16) {
        float4 rv = *(const float4*)(rhat + (size_t)(node*DEG_ + tt)*4);
        s_rhat[h][tt][0] = rv.x; s_rhat[h][tt][1] = rv.y; s_rhat[h][tt][2] = rv.z; s_rhat[h][tt][3] = 0.f;
        s_e[h][tt][tt] = 0.f;                  // diagonal excluded from softmax
    }
    {
        int p = tt >> 3, c8 = tt & 7;
        int e = node*DEG_ + p;
        int se = src[e];
        uint4 aj = *(const uint4*)(xjxi + (size_t)se*128 + c8*8);
        uint4 ai = *(const uint4*)(xjxi + (size_t)node*128 + 64 + c8*8);
        uint4 ae = *(const uint4*)(eproj + (size_t)e*192 + c8*8);
        const unsigned short* pj = (const unsigned short*)&aj;
        const unsigned short* pi = (const unsigned short*)&ai;
        const unsigned short* pe = (const unsigned short*)&ae;
        #pragma unroll
        for (int j = 0; j < 8; ++j)
            s_xij[h][p][c8*8 + j] = b2f(pj[j]) + b2f(pi[j]) + b2f(pe[j]);
    }
    __syncthreads();
    int pp = 0, qq = 0;
    float lg = 0.f;
    if (tt < 120) {                 // unique pair p>q: tt = p(p-1)/2 + q
        pp = (int)((1.0f + sqrtf(8.0f*(float)tt + 1.0f)) * 0.5f);
        qq = tt - ((pp*(pp-1)) >> 1);
        float c = s_rhat[h][pp][0]*s_rhat[h][qq][0] + s_rhat[h][pp][1]*s_rhat[h][qq][1]
                + s_rhat[h][pp][2]*s_rhat[h][qq][2];
        c = fminf(fmaxf(c, -0.999999f), 0.999999f);
        float c2  = 2.0f * c;
        float tk0 = 1.0f;
        float tk1 = c;
        float acc = 0.f;
        const float* xp = &s_xij[h][pp][0];
        const float* xq = &s_xij[h][qq][0];
        #pragma unroll
        for (int k0 = 0; k0 < 64; k0 += 4) {
            float4 xp4 = *(const float4*)(xp + k0);
            float4 xq4 = *(const float4*)(xq + k0);
            float a0 = attn[k0+0], a1 = attn[k0+1], a2 = attn[k0+2], a3 = attn[k0+3];
            float v0 = tk0 + xp4.x + xq4.x;
            acc = fmaf(a0, silu_f(v0), acc);
            { float tn2 = c2*tk1 - tk0; tk0 = tk1; tk1 = tn2; }
            float v1 = tk0 + xp4.y + xq4.y;
            acc = fmaf(a1, silu_f(v1), acc);
            { float tn2 = c2*tk1 - tk0; tk0 = tk1; tk1 = tn2; }
            float v2 = tk0 + xp4.z + xq4.z;
            acc = fmaf(a2, silu_f(v2), acc);
            { float tn2 = c2*tk1 - tk0; tk0 = tk1; tk1 = tn2; }
            float v3 = tk0 + xp4.w + xq4.w;
            acc = fmaf(a3, silu_f(v3), acc);
            { float tn2 = c2*tk1 - tk0; tk0 = tk1; tk1 = tn2; }
        }
        lg = acc;
        s_logit[h][pp][qq] = acc;
        s_logit[h][qq][pp] = acc;
    }
    __syncthreads();
    if (tt < 16) {                  // per-column max (15 fmax, cheap)
        int q = tt;
        float mx = -1e30f;
        #pragma unroll
        for (int p = 0; p < 16; ++p) if (p != q) mx = fmaxf(mx, s_logit[h][p][q]);
        s_m[h][q] = mx;
    }
    __syncthreads();
    if (tt < 120) {                 // parallel exps: 2 per pair thread
        s_e[h][pp][qq] = __expf(lg - s_m[h][qq]);
        s_e[h][qq][pp] = __expf(lg - s_m[h][pp]);
    }
    __syncthreads();
    if (tt < 16) {                  // zi[q] = 1 / sum_p e[p][q]
        int q = tt;
        float z = 0.f;
        #pragma unroll
        for (int p = 0; p < 16; ++p) z += s_e[h][p][q];
        s_zi[h][q] = __builtin_amdgcn_rcpf(z);
    }
    __syncthreads();
    if (tt < 16) {                  // w_p = sum_q e[p][q] * zi[q]
        int p = tt;
        float sw = 0.f;
        #pragma unroll
        for (int q = 0; q < 16; ++q) sw += s_e[h][p][q] * s_zi[h][q];
        s_w[h][p] = sw;
    }
    __syncthreads();
    if (tt < 64) {
        float acc = 0.f;
        #pragma unroll
        for (int p = 0; p < 16; ++p) acc += s_w[h][p] * s_xij[h][p][tt];
        xn[(size_t)node*64 + tt] = f2b(acc);
    }
}

// ---------------- final: out += mean_i (x[i] . Wfc) ----------------
__global__ __launch_bounds__(256) void reduce_kernel(const unsigned short* __restrict__ x,
    const float* __restrict__ Wfc, float* __restrict__ out) {
    __shared__ float s[256];
    int t = threadIdx.x;
    float local = 0.f;
    for (int i = blockIdx.x; i < N_NODES; i += gridDim.x) local += b2f(x[(size_t)i*D_MODEL + t]);
    local *= Wfc[t];
    s[t] = local; __syncthreads();
    for (int off = 128; off > 0; off >>= 1) {
        if (t < off) s[t] += s[t+off];
        __syncthreads();
    }
    if (t == 0) atomicAdd(out, s[0] * (1.0f/(float)N_NODES));
}

extern "C" void kernel_launch(void* const* d_in, const int* in_sizes, int n_in,
                              void* d_out, int out_size, void* d_ws, size_t ws_size,
                              hipStream_t stream) {
    (void)in_sizes; (void)n_in; (void)out_size; (void)ws_size;
    const float* r    = (const float*)d_in[0];
    const int*   an   = (const int*)  d_in[1];
    const int*   src  = (const int*)  d_in[2];
    const float* emb  = (const float*)d_in[6];
    const float* Wsrc = (const float*)d_in[7];
    const float* bsrc = (const float*)d_in[8];
    const float* Wdst = (const float*)d_in[9];
    const float* bdst = (const float*)d_in[10];
    const float* Wedge= (const float*)d_in[11];
    const float* bedge= (const float*)d_in[12];
    const float* attn = (const float*)d_in[13];
    const float* W1   = (const float*)d_in[14];
    const float* b1   = (const float*)d_in[15];
    const float* W2   = (const float*)d_in[16];
    const float* b2   = (const float*)d_in[17];
    const float* Wfc  = (const float*)d_in[18];
    const float* bfc  = (const float*)d_in[19];

    char* ws = (char*)d_ws;
    float* d_d              = (float*)(ws);                    // 384000 B
    float* d_rhat           = (float*)(ws + 384000);           // 1536000 B
    unsigned short* wbf     = (unsigned short*)(ws + 1920000); // 2260992 B
    unsigned short* d_x     = (unsigned short*)(ws + 4180992); // 3072000 B
    unsigned short* d_xjxi  = (unsigned short*)(ws + 7252992); // 1536000 B
    unsigned short* d_eproj = (unsigned short*)(ws + 8788992); // 36864000 B
    unsigned short* d_xn    = (unsigned short*)(ws + 45652992);// 768000 B
    unsigned short* d_h     = (unsigned short*)(ws + 46420992);// 12288000 B
    float* out = (float*)d_out;

    unsigned short* wsrc_bf  = wbf + WSRC_OFF;
    unsigned short* wdst_bf  = wbf + WDST_OFF;
    unsigned short* wedge_bf = wbf + WEDGE_OFF;
    unsigned short* w1_bf    = wbf + W1_OFF;
    unsigned short* w2_bf    = wbf + W2_OFF;

    prep_kernel<<<CVT4_BLOCKS + EMB4_BLOCKS + GEOM_BLOCKS, 256, 0, stream>>>(
        Wsrc, Wdst, Wedge, W1, W2, wbf, an, emb, d_x, r, d_d, d_rhat, out, bfc);
    // eproj for all 3 layers in one pass: [E,192] = RBF(d) @ Wedge^T + bedge
    eproj_kernel<<<750, 256, 0, stream>>>(wedge_bf, bedge, d_d, d_eproj);

    for (int l = 0; l < 3; ++l) {
        mgemm<0,1,64><<<dim3(2,94), 256, 0, stream>>>(
            d_x, 256, wsrc_bf + l*16384, wdst_bf + l*16384, 256,
            bsrc + l*64, bdst + l*64, d_xjxi, 128, N_NODES, 256);
        angle_kernel<<<N_NODES/2, 256, 0, stream>>>(
            d_xjxi, d_eproj + l*64, d_rhat, src, attn + l*64, d_xn);
        mgemm<1,0,64><<<dim3(16,94), 256, 0, stream>>>(
            d_xn, 64, w1_bf + l*65536, (const unsigned short*)nullptr, 64,
            b1 + l*D_FF, (const float*)nullptr, d_h, D_FF, N_NODES, 64);
        mgemm<0,0,64><<<dim3(4,94), 256, 0, stream>>>(
            d_h, 1024, w2_bf + l*262144, (const unsigned short*)nullptr, 1024,
            b2 + l*D_MODEL, (const float*)nullptr, d_x, D_MODEL, N_NODES, 1024);
    }
    reduce_kernel<<<48, 256, 0, stream>>>(d_x, Wfc, out);
}